// Round 2
// baseline (1197.448 us; speedup 1.0000x reference)
//
#include <hip/hip_runtime.h>
#include <hip/hip_bf16.h>
#include <math.h>

#define DIM 1024
#define NEXP 64
#define NN 65
#define DG 256
#define T_TOK 2048
#define THR_EDGE 0.5f

// ---------------- setup kernels (all tiny, fp32) ----------------

// expT[i][j] = relu(sum_k Xp[k][i] * mlp[k][j]);  i<64, j<1024
__global__ __launch_bounds__(256) void k_expT(const float* __restrict__ Xp,
                                              const float* __restrict__ mlp,
                                              float* __restrict__ expT) {
  int i = blockIdx.y;
  int j = blockIdx.x * 256 + threadIdx.x;
  float acc = 0.f;
#pragma unroll 4
  for (int k = 0; k < DIM; ++k)
    acc = fmaf(Xp[k * NEXP + i], mlp[k * DIM + j], acc);
  expT[i * DIM + j] = fmaxf(acc, 0.f);
}

// W01[i][d] = sum_k W0[i][k] * W1[k][d]   (W0@W1, so v = xt@W01)
__global__ __launch_bounds__(256) void k_W01(const float* __restrict__ W0,
                                             const float* __restrict__ W1,
                                             float* __restrict__ W01) {
  int i = blockIdx.x;
  int d = threadIdx.x;
  float acc = 0.f;
#pragma unroll 4
  for (int k = 0; k < DG; ++k)
    acc = fmaf(W0[i * DG + k], W1[k * DG + d], acc);
  W01[i * DG + d] = acc;
}

// w3p[i] = sum_k W3[i][k] * pw[k]   (W3 @ proj_w collapses last layer)
__global__ __launch_bounds__(256) void k_w3p(const float* __restrict__ W3,
                                             const float* __restrict__ pw,
                                             float* __restrict__ w3p) {
  int i = threadIdx.x;
  float acc = 0.f;
#pragma unroll 4
  for (int k = 0; k < DIM; ++k)
    acc = fmaf(W3[i * DIM + k], pw[k], acc);
  w3p[i] = acc;
}

// D[i][j] = dot(expT[i], expT[j])  (cos numerators + squared norms on diag)
__global__ __launch_bounds__(64) void k_cos(const float* __restrict__ expT,
                                            float* __restrict__ D) {
  int i = blockIdx.x;
  int j = threadIdx.x;
  float acc = 0.f;
#pragma unroll 8
  for (int d = 0; d < DIM; ++d)
    acc = fmaf(expT[i * DIM + d], expT[j * DIM + d], acc);
  D[i * NEXP + j] = acc;
}

// Build normalized adjacency Ahat [65][65] and q = Ahat @ a0
__global__ __launch_bounds__(256) void k_buildA(const float* __restrict__ D,
                                                float* __restrict__ Ahat,
                                                float* __restrict__ q) {
  __shared__ float nrm[NEXP];
  __shared__ float Ar[NN][NN];
  __shared__ float Al[NN][NN];
  __shared__ float dd[NN];
  __shared__ float a0[NN];
  int tid = threadIdx.x;
  if (tid < NEXP) nrm[tid] = fmaxf(sqrtf(D[tid * NEXP + tid]), 1e-8f);
  __syncthreads();
  for (int e = tid; e < NN * NN; e += 256) {
    int n = e / NN, m = e - n * NN;
    float v = 0.f;
    if (n == m) v = 1.f;                              // self loop
    else if (m == NEXP) v = (n < NEXP) ? 1.f : 0.f;   // token -> every expert
    else if (n < NEXP && m < n) {                     // edge m->n for m<n
      float c = D[m * NEXP + n] / (nrm[m] * nrm[n]);
      v = (c > THR_EDGE) ? 1.f : 0.f;
    }
    Ar[n][m] = v;
  }
  __syncthreads();
  if (tid < NN) {
    float s = 0.f;
    for (int m = 0; m < NN; ++m) s += Ar[tid][m];
    dd[tid] = 1.0f / sqrtf(s);
  }
  __syncthreads();
  for (int e = tid; e < NN * NN; e += 256) {
    int n = e / NN, m = e - n * NN;
    float v = Ar[n][m] * dd[n] * dd[m];
    Al[n][m] = v;
    Ahat[e] = v;
  }
  __syncthreads();
  if (tid < NN) a0[tid] = Al[tid][NEXP];
  __syncthreads();
  if (tid < NN) {
    float s = 0.f;
    for (int m = 0; m < NN; ++m) s = fmaf(Al[tid][m], a0[m], s);
    q[tid] = s;
  }
}

// expW[m][d] = sum_k expT[m][k] * W0[k][d]
__global__ __launch_bounds__(256) void k_expW(const float* __restrict__ expT,
                                              const float* __restrict__ W0,
                                              float* __restrict__ expW) {
  int m = blockIdx.x, d = threadIdx.x;
  float acc = 0.f;
#pragma unroll 4
  for (int k = 0; k < DIM; ++k)
    acc = fmaf(expT[m * DIM + k], W0[k * DG + d], acc);
  expW[m * DG + d] = acc;
}

// CW1[n][d] = ((Ahat[:, :64] @ expW) @ W1)[n][d]
__global__ __launch_bounds__(256) void k_CW1(const float* __restrict__ Ahat,
                                             const float* __restrict__ expW,
                                             const float* __restrict__ W1,
                                             float* __restrict__ CW1) {
  __shared__ float c0[DG];
  int n = blockIdx.x, d = threadIdx.x;
  float acc = 0.f;
  for (int m = 0; m < NEXP; ++m)
    acc = fmaf(Ahat[n * NN + m], expW[m * DG + d], acc);
  c0[d] = acc;
  __syncthreads();
  float b = 0.f;
#pragma unroll 4
  for (int k = 0; k < DG; ++k)
    b = fmaf(c0[k], W1[k * DG + d], b);
  CW1[n * DG + d] = b;
}

// P[n][d] = (Ahat @ CW1)[n][d]
__global__ __launch_bounds__(256) void k_P(const float* __restrict__ Ahat,
                                           const float* __restrict__ CW1,
                                           float* __restrict__ P) {
  int n = blockIdx.x, d = threadIdx.x;
  float acc = 0.f;
  for (int m = 0; m < NN; ++m)
    acc = fmaf(Ahat[n * NN + m], CW1[m * DG + d], acc);
  P[n * DG + d] = acc;
}

// ---------------- fp32 tiled GEMM (64x64 tile, 4x4 micro) ----------------
template <bool RELU>
__global__ __launch_bounds__(256) void k_gemm(const float* __restrict__ A,
                                              const float* __restrict__ B,
                                              float* __restrict__ C,
                                              int M, int N, int K) {
  __shared__ float As[64][17];
  __shared__ float Bs[16][64];
  int tid = threadIdx.x;
  int tx = tid & 15, ty = tid >> 4;
  int bm0 = blockIdx.y * 64, bn0 = blockIdx.x * 64;
  int ar = tid >> 2, ac = (tid & 3) * 4;
  int brow = tid >> 4, bcol = (tid & 15) * 4;
  float acc[4][4] = {};
  for (int k0 = 0; k0 < K; k0 += 16) {
    float4 av = *(const float4*)&A[(size_t)(bm0 + ar) * K + k0 + ac];
    float4 bv = *(const float4*)&B[(size_t)(k0 + brow) * N + bn0 + bcol];
    As[ar][ac + 0] = av.x; As[ar][ac + 1] = av.y;
    As[ar][ac + 2] = av.z; As[ar][ac + 3] = av.w;
    *(float4*)&Bs[brow][bcol] = bv;
    __syncthreads();
#pragma unroll
    for (int kk = 0; kk < 16; ++kk) {
      float a0 = As[ty * 4 + 0][kk], a1 = As[ty * 4 + 1][kk];
      float a2 = As[ty * 4 + 2][kk], a3 = As[ty * 4 + 3][kk];
      float4 b = *(const float4*)&Bs[kk][tx * 4];
      acc[0][0] = fmaf(a0, b.x, acc[0][0]); acc[0][1] = fmaf(a0, b.y, acc[0][1]);
      acc[0][2] = fmaf(a0, b.z, acc[0][2]); acc[0][3] = fmaf(a0, b.w, acc[0][3]);
      acc[1][0] = fmaf(a1, b.x, acc[1][0]); acc[1][1] = fmaf(a1, b.y, acc[1][1]);
      acc[1][2] = fmaf(a1, b.z, acc[1][2]); acc[1][3] = fmaf(a1, b.w, acc[1][3]);
      acc[2][0] = fmaf(a2, b.x, acc[2][0]); acc[2][1] = fmaf(a2, b.y, acc[2][1]);
      acc[2][2] = fmaf(a2, b.z, acc[2][2]); acc[2][3] = fmaf(a2, b.w, acc[2][3]);
      acc[3][0] = fmaf(a3, b.x, acc[3][0]); acc[3][1] = fmaf(a3, b.y, acc[3][1]);
      acc[3][2] = fmaf(a3, b.z, acc[3][2]); acc[3][3] = fmaf(a3, b.w, acc[3][3]);
    }
    __syncthreads();
  }
#pragma unroll
  for (int i = 0; i < 4; ++i) {
    float4 v;
    v.x = acc[i][0]; v.y = acc[i][1]; v.z = acc[i][2]; v.w = acc[i][3];
    if (RELU) {
      v.x = fmaxf(v.x, 0.f); v.y = fmaxf(v.y, 0.f);
      v.z = fmaxf(v.z, 0.f); v.w = fmaxf(v.w, 0.f);
    }
    *(float4*)&C[(size_t)(bm0 + ty * 4 + i) * N + bn0 + tx * 4] = v;
  }
}

// ---------------- the hot kernel: fused GCN middle ----------------
// block = (t-tile of 64 tokens, node n). Computes
//   G[t][k]  = sum_m Ahat[n][m] * relu(P[m][k] + q[m]*V[t][k])   (A-mix, regs)
//   h2[t][d] = relu(sum_k G[t][k] * W2[k][d])                    (LDS GEMM)
//   s2[n][t] = sum_d h2[t][d] * w3p[d]                           (reduce)
__global__ __launch_bounds__(256) void k_gcn(const float* __restrict__ V,
                                             const float* __restrict__ P,
                                             const float* __restrict__ Ahat,
                                             const float* __restrict__ q,
                                             const float* __restrict__ W2,
                                             const float* __restrict__ w3p,
                                             float* __restrict__ s2) {
  __shared__ float Gs[64][256];     // exactly 64 KiB
  int tid = threadIdx.x;
  int n = blockIdx.y;
  int t0 = blockIdx.x * 64;
  float wp = w3p[tid];

  // phase 1: A-mix with V-tile column + G accumulators in registers
  float v[64];
#pragma unroll
  for (int t = 0; t < 64; ++t) v[t] = V[(size_t)(t0 + t) * DG + tid];
  float G[64];
#pragma unroll
  for (int t = 0; t < 64; ++t) G[t] = 0.f;
  for (int m = 0; m < NN; ++m) {     // rolled: keeps code in I-cache
    float p = P[m * DG + tid];       // coalesced, L2-hot
    float a = Ahat[n * NN + m];      // wave-uniform -> scalar
    float s = q[m];                  // wave-uniform -> scalar
#pragma unroll
    for (int t = 0; t < 64; ++t)
      G[t] = fmaf(a, fmaxf(fmaf(s, v[t], p), 0.f), G[t]);
  }
#pragma unroll
  for (int t = 0; t < 64; ++t) Gs[t][tid] = G[t];
  __syncthreads();

  // phase 2: h2 = relu(G @ W2); thread owns column d=tid, 64 token accs
  float acc[64];
#pragma unroll
  for (int t = 0; t < 64; ++t) acc[t] = 0.f;
  for (int k4 = 0; k4 < 64; ++k4) {
    float w0 = W2[(k4 * 4 + 0) * DG + tid];
    float w1 = W2[(k4 * 4 + 1) * DG + tid];
    float w2v = W2[(k4 * 4 + 2) * DG + tid];
    float w3v = W2[(k4 * 4 + 3) * DG + tid];
#pragma unroll
    for (int t = 0; t < 64; ++t) {
      float4 g = *(const float4*)&Gs[t][k4 * 4];   // broadcast b128
      acc[t] = fmaf(g.x, w0, fmaf(g.y, w1, fmaf(g.z, w2v, fmaf(g.w, w3v, acc[t]))));
    }
  }
  __syncthreads();   // all Gs reads done; reuse Gs as reduction scratch

  // phase 3: s2 partials (relu -> *w3p -> reduce over d)
  int lane = tid & 63, w = tid >> 6;
  float* red = &Gs[0][0];
  for (int t = 0; t < 64; ++t) {
    float val = fmaxf(acc[t], 0.f) * wp;
#pragma unroll
    for (int off = 32; off > 0; off >>= 1)
      val += __shfl_down(val, off, 64);
    if (lane == 0) red[w * 64 + t] = val;
  }
  __syncthreads();
  if (tid < 64) {
    float sv = red[tid] + red[64 + tid] + red[128 + tid] + red[192 + tid];
    s2[(size_t)n * T_TOK + t0 + tid] = sv;
  }
}

// ---------------- final: scores = Ahat[:64,:] @ s2[:,t], softmax ----------------
__global__ __launch_bounds__(64) void k_final(const float* __restrict__ s2,
                                              const float* __restrict__ Ahat,
                                              float* __restrict__ out) {
  __shared__ float s2l[NN];
  int t = blockIdx.x;
  int j = threadIdx.x;
  s2l[j] = s2[(size_t)j * T_TOK + t];
  if (j == 0) s2l[NEXP] = s2[(size_t)NEXP * T_TOK + t];
  __syncthreads();
  float sc = 0.f;
  for (int m = 0; m < NN; ++m)
    sc = fmaf(Ahat[j * NN + m], s2l[m], sc);
  float mx = sc;
#pragma unroll
  for (int off = 32; off > 0; off >>= 1)
    mx = fmaxf(mx, __shfl_xor(mx, off, 64));
  float e = expf(sc - mx);
  float sum = e;
#pragma unroll
  for (int off = 32; off > 0; off >>= 1)
    sum += __shfl_xor(sum, off, 64);
  out[(size_t)t * NEXP + j] = e / sum;
}

// ---------------- launch ----------------
extern "C" void kernel_launch(void* const* d_in, const int* in_sizes, int n_in,
                              void* d_out, int out_size, void* d_ws, size_t ws_size,
                              hipStream_t stream) {
  (void)in_sizes; (void)n_in; (void)out_size; (void)ws_size;
  const float* x   = (const float*)d_in[0];
  const float* Xp  = (const float*)d_in[1];
  const float* mlp = (const float*)d_in[2];
  const float* W0  = (const float*)d_in[3];
  const float* W1  = (const float*)d_in[4];
  const float* W2  = (const float*)d_in[5];
  const float* W3  = (const float*)d_in[6];
  const float* pw  = (const float*)d_in[7];
  float* out = (float*)d_out;
  float* ws = (float*)d_ws;

  // workspace layout (floats), total ~3.15M floats (~12.6 MB)
  float* expT = ws;                 // 64*1024
  float* W01  = ws + 65536;         // 1024*256
  float* w3p  = ws + 327680;        // 256
  float* D    = ws + 328704;        // 64*64
  float* Ahat = ws + 332800;        // 65*65
  float* q    = ws + 340992;        // 65
  float* expW = ws + 342016;        // 64*256
  float* CW1  = ws + 358400;        // 65*256
  float* P    = ws + 375808;        // 65*256
  float* XT   = ws + 393216;        // 2048*1024
  float* V    = ws + 2490368;       // 2048*256
  float* s2   = ws + 3014656;       // 65*2048

  k_expT<<<dim3(4, 64), dim3(256), 0, stream>>>(Xp, mlp, expT);
  k_W01<<<dim3(1024), dim3(256), 0, stream>>>(W0, W1, W01);
  k_w3p<<<dim3(1), dim3(256), 0, stream>>>(W3, pw, w3p);
  k_cos<<<dim3(64), dim3(64), 0, stream>>>(expT, D);
  k_buildA<<<dim3(1), dim3(256), 0, stream>>>(D, Ahat, q);
  k_expW<<<dim3(64), dim3(256), 0, stream>>>(expT, W0, expW);
  k_CW1<<<dim3(65), dim3(256), 0, stream>>>(Ahat, expW, W1, CW1);
  k_P<<<dim3(65), dim3(256), 0, stream>>>(Ahat, CW1, P);
  // XT = relu(x @ mlp_w)   [2048,1024]
  k_gemm<true><<<dim3(16, 32), dim3(256), 0, stream>>>(x, mlp, XT, 2048, 1024, 1024);
  // V = XT @ W01           [2048,256]
  k_gemm<false><<<dim3(4, 32), dim3(256), 0, stream>>>(XT, W01, V, 2048, 256, 1024);
  // fused GCN middle -> s2 [65,2048]
  k_gcn<<<dim3(32, 65), dim3(256), 0, stream>>>(V, P, Ahat, q, W2, w3p, s2);
  // scores + softmax -> out [2048,64]
  k_final<<<dim3(2048), dim3(64), 0, stream>>>(s2, Ahat, out);
}

// Round 4
// 898.814 us; speedup vs baseline: 1.3323x; 1.3323x over previous
//
#include <hip/hip_runtime.h>
#include <hip/hip_bf16.h>
#include <math.h>

#define DIM 1024
#define NEXP 64
#define NN 65
#define DG 256
#define T_TOK 2048
#define THR_EDGE 0.5f

// ---------------- setup kernels (all tiny, fp32) ----------------

// expT[i][j] = relu(sum_k Xp[k][i] * mlp[k][j]); 4 i's per block to reuse mlp reads.
// Also writes expTT[j][i] (transposed) for coalesced k_cos.
__global__ __launch_bounds__(256) void k_expT(const float* __restrict__ Xp,
                                              const float* __restrict__ mlp,
                                              float* __restrict__ expT,
                                              float* __restrict__ expTT) {
  int i0 = blockIdx.y * 4;
  int j = blockIdx.x * 256 + threadIdx.x;
  float acc0 = 0.f, acc1 = 0.f, acc2 = 0.f, acc3 = 0.f;
  for (int k = 0; k < DIM; ++k) {
    float m = mlp[(size_t)k * DIM + j];          // coalesced
    const float* xr = &Xp[(size_t)k * NEXP + i0]; // uniform -> s_load
    acc0 = fmaf(xr[0], m, acc0);
    acc1 = fmaf(xr[1], m, acc1);
    acc2 = fmaf(xr[2], m, acc2);
    acc3 = fmaf(xr[3], m, acc3);
  }
  acc0 = fmaxf(acc0, 0.f); acc1 = fmaxf(acc1, 0.f);
  acc2 = fmaxf(acc2, 0.f); acc3 = fmaxf(acc3, 0.f);
  expT[(size_t)(i0 + 0) * DIM + j] = acc0;
  expT[(size_t)(i0 + 1) * DIM + j] = acc1;
  expT[(size_t)(i0 + 2) * DIM + j] = acc2;
  expT[(size_t)(i0 + 3) * DIM + j] = acc3;
  expTT[(size_t)j * NEXP + i0 + 0] = acc0;
  expTT[(size_t)j * NEXP + i0 + 1] = acc1;
  expTT[(size_t)j * NEXP + i0 + 2] = acc2;
  expTT[(size_t)j * NEXP + i0 + 3] = acc3;
}

// W01[i][d] = sum_k W0[i][k] * W1[k][d]
__global__ __launch_bounds__(256) void k_W01(const float* __restrict__ W0,
                                             const float* __restrict__ W1,
                                             float* __restrict__ W01) {
  int i = blockIdx.x;
  int d = threadIdx.x;
  float acc = 0.f;
#pragma unroll 4
  for (int k = 0; k < DG; ++k)
    acc = fmaf(W0[i * DG + k], W1[k * DG + d], acc);
  W01[i * DG + d] = acc;
}

// w3p[i] = sum_k W3[i][k] * pw[k]  — 2-stage: coalesced strips + wave reduce
__global__ __launch_bounds__(256) void k_w3p(const float* __restrict__ W3,
                                             const float* __restrict__ pw,
                                             float* __restrict__ w3p) {
  __shared__ float red[4];
  int tid = threadIdx.x;
  int lane = tid & 63, w = tid >> 6;
  float pv0 = pw[tid], pv1 = pw[tid + 256], pv2 = pw[tid + 512], pv3 = pw[tid + 768];
  for (int i = 0; i < DG; ++i) {
    const float* r = &W3[(size_t)i * DIM];
    float s = r[tid] * pv0 + r[tid + 256] * pv1 + r[tid + 512] * pv2 + r[tid + 768] * pv3;
#pragma unroll
    for (int off = 32; off > 0; off >>= 1)
      s += __shfl_down(s, off, 64);
    if (lane == 0) red[w] = s;
    __syncthreads();
    if (tid == 0) w3p[i] = red[0] + red[1] + red[2] + red[3];
    __syncthreads();
  }
}

// D[i][j] = dot(exp_i, exp_j) via transposed expTT for coalescing
__global__ __launch_bounds__(64) void k_cos(const float* __restrict__ expTT,
                                            float* __restrict__ D) {
  int i = blockIdx.x;
  int j = threadIdx.x;
  float acc = 0.f;
  for (int d = 0; d < DIM; ++d) {
    float ei = expTT[(size_t)d * NEXP + i];   // uniform -> s_load
    float ej = expTT[(size_t)d * NEXP + j];   // coalesced 256B
    acc = fmaf(ei, ej, acc);
  }
  D[i * NEXP + j] = acc;
}

// Build normalized adjacency Ahat [65][65] and q = Ahat @ a0
__global__ __launch_bounds__(256) void k_buildA(const float* __restrict__ D,
                                                float* __restrict__ Ahat,
                                                float* __restrict__ q) {
  __shared__ float nrm[NEXP];
  __shared__ float Ar[NN][NN];
  __shared__ float Al[NN][NN];
  __shared__ float dd[NN];
  __shared__ float a0[NN];
  int tid = threadIdx.x;
  if (tid < NEXP) nrm[tid] = fmaxf(sqrtf(D[tid * NEXP + tid]), 1e-8f);
  __syncthreads();
  for (int e = tid; e < NN * NN; e += 256) {
    int n = e / NN, m = e - n * NN;
    float v = 0.f;
    if (n == m) v = 1.f;                              // self loop
    else if (m == NEXP) v = (n < NEXP) ? 1.f : 0.f;   // token -> each expert
    else if (n < NEXP && m < n) {                     // edge m->n for m<n
      float c = D[m * NEXP + n] / (nrm[m] * nrm[n]);
      v = (c > THR_EDGE) ? 1.f : 0.f;
    }
    Ar[n][m] = v;
  }
  __syncthreads();
  if (tid < NN) {
    float s = 0.f;
    for (int m = 0; m < NN; ++m) s += Ar[tid][m];
    dd[tid] = 1.0f / sqrtf(s);
  }
  __syncthreads();
  for (int e = tid; e < NN * NN; e += 256) {
    int n = e / NN, m = e - n * NN;
    float v = Ar[n][m] * dd[n] * dd[m];
    Al[n][m] = v;
    Ahat[e] = v;
  }
  __syncthreads();
  if (tid < NN) a0[tid] = Al[tid][NEXP];
  __syncthreads();
  if (tid < NN) {
    float s = 0.f;
    for (int m = 0; m < NN; ++m) s = fmaf(Al[tid][m], a0[m], s);
    q[tid] = s;
  }
}

// expW[m][d] = sum_k expT[m][k] * W0[k][d]
__global__ __launch_bounds__(256) void k_expW(const float* __restrict__ expT,
                                              const float* __restrict__ W0,
                                              float* __restrict__ expW) {
  int m = blockIdx.x, d = threadIdx.x;
  float acc = 0.f;
#pragma unroll 4
  for (int k = 0; k < DIM; ++k)
    acc = fmaf(expT[m * DIM + k], W0[k * DG + d], acc);
  expW[m * DG + d] = acc;
}

// CW1[n][d] = ((Ahat[:, :64] @ expW) @ W1)[n][d]
__global__ __launch_bounds__(256) void k_CW1(const float* __restrict__ Ahat,
                                             const float* __restrict__ expW,
                                             const float* __restrict__ W1,
                                             float* __restrict__ CW1) {
  __shared__ float c0[DG];
  int n = blockIdx.x, d = threadIdx.x;
  float acc = 0.f;
  for (int m = 0; m < NEXP; ++m)
    acc = fmaf(Ahat[n * NN + m], expW[m * DG + d], acc);
  c0[d] = acc;
  __syncthreads();
  float b = 0.f;
#pragma unroll 4
  for (int k = 0; k < DG; ++k)
    b = fmaf(c0[k], W1[k * DG + d], b);
  CW1[n * DG + d] = b;
}

// P[n][d] = (Ahat @ CW1)[n][d]
__global__ __launch_bounds__(256) void k_P(const float* __restrict__ Ahat,
                                           const float* __restrict__ CW1,
                                           float* __restrict__ P) {
  int n = blockIdx.x, d = threadIdx.x;
  float acc = 0.f;
  for (int m = 0; m < NN; ++m)
    acc = fmaf(Ahat[n * NN + m], CW1[m * DG + d], acc);
  P[n * DG + d] = acc;
}

// ---------------- fp32 tiled GEMM (64x64 tile, 4x4 micro) ----------------
template <bool RELU>
__global__ __launch_bounds__(256) void k_gemm(const float* __restrict__ A,
                                              const float* __restrict__ B,
                                              float* __restrict__ C,
                                              int M, int N, int K) {
  __shared__ float As[64][17];
  __shared__ float Bs[16][64];
  int tid = threadIdx.x;
  int tx = tid & 15, ty = tid >> 4;
  int bm0 = blockIdx.y * 64, bn0 = blockIdx.x * 64;
  int ar = tid >> 2, ac = (tid & 3) * 4;
  int brow = tid >> 4, bcol = (tid & 15) * 4;
  float acc[4][4] = {};
  for (int k0 = 0; k0 < K; k0 += 16) {
    float4 av = *(const float4*)&A[(size_t)(bm0 + ar) * K + k0 + ac];
    float4 bv = *(const float4*)&B[(size_t)(k0 + brow) * N + bn0 + bcol];
    As[ar][ac + 0] = av.x; As[ar][ac + 1] = av.y;
    As[ar][ac + 2] = av.z; As[ar][ac + 3] = av.w;
    *(float4*)&Bs[brow][bcol] = bv;
    __syncthreads();
#pragma unroll
    for (int kk = 0; kk < 16; ++kk) {
      float a0 = As[ty * 4 + 0][kk], a1 = As[ty * 4 + 1][kk];
      float a2 = As[ty * 4 + 2][kk], a3 = As[ty * 4 + 3][kk];
      float4 b = *(const float4*)&Bs[kk][tx * 4];
      acc[0][0] = fmaf(a0, b.x, acc[0][0]); acc[0][1] = fmaf(a0, b.y, acc[0][1]);
      acc[0][2] = fmaf(a0, b.z, acc[0][2]); acc[0][3] = fmaf(a0, b.w, acc[0][3]);
      acc[1][0] = fmaf(a1, b.x, acc[1][0]); acc[1][1] = fmaf(a1, b.y, acc[1][1]);
      acc[1][2] = fmaf(a1, b.z, acc[1][2]); acc[1][3] = fmaf(a1, b.w, acc[1][3]);
      acc[2][0] = fmaf(a2, b.x, acc[2][0]); acc[2][1] = fmaf(a2, b.y, acc[2][1]);
      acc[2][2] = fmaf(a2, b.z, acc[2][2]); acc[2][3] = fmaf(a2, b.w, acc[2][3]);
      acc[3][0] = fmaf(a3, b.x, acc[3][0]); acc[3][1] = fmaf(a3, b.y, acc[3][1]);
      acc[3][2] = fmaf(a3, b.z, acc[3][2]); acc[3][3] = fmaf(a3, b.w, acc[3][3]);
    }
    __syncthreads();
  }
#pragma unroll
  for (int i = 0; i < 4; ++i) {
    float4 v;
    v.x = acc[i][0]; v.y = acc[i][1]; v.z = acc[i][2]; v.w = acc[i][3];
    if (RELU) {
      v.x = fmaxf(v.x, 0.f); v.y = fmaxf(v.y, 0.f);
      v.z = fmaxf(v.z, 0.f); v.w = fmaxf(v.w, 0.f);
    }
    *(float4*)&C[(size_t)(bm0 + ty * 4 + i) * N + bn0 + tx * 4] = v;
  }
}

// ---------------- k_mix: G[nn][t][k] = sum_m Ahat[n0+nn][m] * R[t][m][k] ----------------
// R computed once per thread (not per n): r[m] = relu(P[m][k] + q[m]*V[t][k])
__global__ __launch_bounds__(256) void k_mix(const float* __restrict__ V,
                                             const float* __restrict__ P,
                                             const float* __restrict__ Ahat,
                                             const float* __restrict__ q,
                                             float* __restrict__ Gc,
                                             int n0, int nch) {
  int t = blockIdx.x;
  int k = threadIdx.x;
  float v = V[(size_t)t * DG + k];
  float r[NN];
#pragma unroll
  for (int m = 0; m < NN; ++m)
    r[m] = fmaxf(fmaf(q[m], v, P[m * DG + k]), 0.f);
  for (int nn = 0; nn < nch; ++nn) {
    const float* arow = &Ahat[(size_t)(n0 + nn) * NN];  // uniform -> s_loads
    float acc = 0.f;
#pragma unroll
    for (int m = 0; m < NN; ++m)
      acc = fmaf(arow[m], r[m], acc);
    Gc[((size_t)nn * T_TOK + t) * DG + k] = acc;
  }
}

// ---------------- k_zgemm: s2T[t][n] = sum_d relu((G[n,t]@W2)[d]) * w3p[d] ----------------
// Block = (t-tile of 128, one chunk-local n). Lane owns t=lane and t=lane+64,
// 64 d's per wave (wave w -> d in [w*64, w*64+64)). A from LDS (pad 37 -> 2-way free),
// B (W2 row) via readfirstlane-uniform pointer -> SMEM s_loads (no LDS, no VMEM).
#define ZTT 128
__global__ __launch_bounds__(256, 3) void k_zgemm(const float* __restrict__ Gc,
                                                  const float* __restrict__ W2,
                                                  const float* __restrict__ w3p,
                                                  float* __restrict__ s2T,
                                                  int n0) {
  __shared__ float As[ZTT][37];
  int tid = threadIdx.x;
  int ny = blockIdx.y;
  int t0 = blockIdx.x * ZTT;
  int lane = tid & 63, w = tid >> 6;
  int wofs = __builtin_amdgcn_readfirstlane(w * 64);

  float acc0[64], acc1[64];
#pragma unroll
  for (int j = 0; j < 64; ++j) { acc0[j] = 0.f; acc1[j] = 0.f; }

  const float* Abase = Gc + ((size_t)ny * T_TOK + t0) * DG;

  for (int k0 = 0; k0 < DG; k0 += 32) {
    // stage A: 128 rows x 32 cols
    {
      int r = tid >> 1, c = (tid & 1) * 16;
      const float* src = Abase + (size_t)r * DG + k0 + c;
      float4 x0 = *(const float4*)(src + 0);
      float4 x1 = *(const float4*)(src + 4);
      float4 x2 = *(const float4*)(src + 8);
      float4 x3 = *(const float4*)(src + 12);
      float* dst = &As[r][c];
      dst[0] = x0.x; dst[1] = x0.y; dst[2] = x0.z; dst[3] = x0.w;
      dst[4] = x1.x; dst[5] = x1.y; dst[6] = x1.z; dst[7] = x1.w;
      dst[8] = x2.x; dst[9] = x2.y; dst[10] = x2.z; dst[11] = x2.w;
      dst[12] = x3.x; dst[13] = x3.y; dst[14] = x3.z; dst[15] = x3.w;
    }
    __syncthreads();
#pragma unroll 2
    for (int kk = 0; kk < 32; ++kk) {
      float a0 = As[lane][kk];
      float a1 = As[lane + 64][kk];
      const float* brow = &W2[(size_t)(k0 + kk) * DG + wofs];  // uniform -> s_load
#pragma unroll
      for (int j = 0; j < 64; ++j) {
        float b = brow[j];
        acc0[j] = fmaf(a0, b, acc0[j]);
        acc1[j] = fmaf(a1, b, acc1[j]);
      }
    }
    __syncthreads();
  }

  // epilogue: relu -> *w3p -> reduce over d (64 per wave, then 4 waves)
  const float* wpr = &w3p[wofs];   // uniform
  float part0 = 0.f, part1 = 0.f;
#pragma unroll
  for (int j = 0; j < 64; ++j) {
    float wpj = wpr[j];
    part0 = fmaf(fmaxf(acc0[j], 0.f), wpj, part0);
    part1 = fmaf(fmaxf(acc1[j], 0.f), wpj, part1);
  }
  float* red = &As[0][0];          // reuse As (all reads done at last barrier)
  red[w * ZTT + lane] = part0;
  red[w * ZTT + 64 + lane] = part1;
  __syncthreads();
  if (tid < ZTT) {
    float s = red[tid] + red[ZTT + tid] + red[2 * ZTT + tid] + red[3 * ZTT + tid];
    s2T[(size_t)(t0 + tid) * NN + (n0 + ny)] = s;
  }
}

// ---------------- final: scores[t][j] = sum_m Ahat[j][m]*s2T[t][m]; softmax ----------------
__global__ __launch_bounds__(64) void k_final(const float* __restrict__ s2T,
                                              const float* __restrict__ Ahat,
                                              float* __restrict__ out) {
  __shared__ float s2l[NN];
  int t = blockIdx.x;
  int j = threadIdx.x;
  s2l[j] = s2T[(size_t)t * NN + j];
  if (j == 0) s2l[NEXP] = s2T[(size_t)t * NN + NEXP];
  __syncthreads();
  float sc = 0.f;
  for (int m = 0; m < NN; ++m)
    sc = fmaf(Ahat[j * NN + m], s2l[m], sc);
  float mx = sc;
#pragma unroll
  for (int off = 32; off > 0; off >>= 1)
    mx = fmaxf(mx, __shfl_xor(mx, off, 64));
  float e = expf(sc - mx);
  float sum = e;
#pragma unroll
  for (int off = 32; off > 0; off >>= 1)
    sum += __shfl_xor(sum, off, 64);
  out[(size_t)t * NEXP + j] = e / sum;
}

// ---------------- launch ----------------
extern "C" void kernel_launch(void* const* d_in, const int* in_sizes, int n_in,
                              void* d_out, int out_size, void* d_ws, size_t ws_size,
                              hipStream_t stream) {
  (void)in_sizes; (void)n_in; (void)out_size; (void)ws_size;
  const float* x   = (const float*)d_in[0];
  const float* Xp  = (const float*)d_in[1];
  const float* mlp = (const float*)d_in[2];
  const float* W0  = (const float*)d_in[3];
  const float* W1  = (const float*)d_in[4];
  const float* W2  = (const float*)d_in[5];
  const float* W3  = (const float*)d_in[6];
  const float* pw  = (const float*)d_in[7];
  float* out = (float*)d_out;
  float* ws = (float*)d_ws;

  // workspace layout (floats), total ~20.5M floats (~82 MB)
  float* expT  = ws + 0;         // 65536
  float* expTT = ws + 65536;     // 65536
  float* W01   = ws + 131072;    // 262144
  float* w3p   = ws + 393216;    // 256
  float* D     = ws + 393472;    // 4096
  float* Ahat  = ws + 397568;    // 4225 (+pad)
  float* q     = ws + 401808;    // 65 (+pad)
  float* expW  = ws + 401888;    // 16384
  float* CW1   = ws + 418272;    // 16640
  float* P     = ws + 434912;    // 16640
  float* s2T   = ws + 451552;    // 2048*65 = 133120
  float* XT    = ws + 584672;    // 2048*1024
  float* V     = ws + 2681824;   // 2048*256
  float* Gc    = ws + 3206112;   // 33*2048*256 = 17301504

  k_expT<<<dim3(4, 16), dim3(256), 0, stream>>>(Xp, mlp, expT, expTT);
  k_W01<<<dim3(1024), dim3(256), 0, stream>>>(W0, W1, W01);
  k_w3p<<<dim3(1), dim3(256), 0, stream>>>(W3, pw, w3p);
  k_cos<<<dim3(64), dim3(64), 0, stream>>>(expTT, D);
  k_buildA<<<dim3(1), dim3(256), 0, stream>>>(D, Ahat, q);
  k_expW<<<dim3(64), dim3(256), 0, stream>>>(expT, W0, expW);
  k_CW1<<<dim3(65), dim3(256), 0, stream>>>(Ahat, expW, W1, CW1);
  k_P<<<dim3(65), dim3(256), 0, stream>>>(Ahat, CW1, P);
  // XT = relu(x @ mlp_w)   [2048,1024]
  k_gemm<true><<<dim3(16, 32), dim3(256), 0, stream>>>(x, mlp, XT, 2048, 1024, 1024);
  // V = XT @ W01           [2048,256]
  k_gemm<false><<<dim3(4, 32), dim3(256), 0, stream>>>(XT, W01, V, 2048, 256, 1024);
  // chunked: G = Ahat-mix of R, then s2 = reduce(relu(G@W2)*w3p)
  k_mix<<<dim3(T_TOK), dim3(256), 0, stream>>>(V, P, Ahat, q, Gc, 0, 33);
  k_zgemm<<<dim3(16, 33), dim3(256), 0, stream>>>(Gc, W2, w3p, s2T, 0);
  k_mix<<<dim3(T_TOK), dim3(256), 0, stream>>>(V, P, Ahat, q, Gc, 33, 32);
  k_zgemm<<<dim3(16, 32), dim3(256), 0, stream>>>(Gc, W2, w3p, s2T, 33);
  // scores + softmax -> out [2048,64]
  k_final<<<dim3(T_TOK), dim3(64), 0, stream>>>(s2T, Ahat, out);
}

// Round 7
// 747.509 us; speedup vs baseline: 1.6019x; 1.2024x over previous
//
#include <hip/hip_runtime.h>
#include <hip/hip_bf16.h>
#include <math.h>

#define DIM 1024
#define NEXP 64
#define NN 65
#define DG 256
#define T_TOK 2048
#define THR_EDGE 0.5f

// ---------------- setup kernels (all tiny, fp32) ----------------

// expT[i][j] = relu(sum_k Xp[k][i] * mlp[k][j]); 4 i's per block to reuse mlp reads.
// Also writes expTT[j][i] (transposed) for coalesced k_cos.
__global__ __launch_bounds__(256) void k_expT(const float* __restrict__ Xp,
                                              const float* __restrict__ mlp,
                                              float* __restrict__ expT,
                                              float* __restrict__ expTT) {
  int i0 = blockIdx.y * 4;
  int j = blockIdx.x * 256 + threadIdx.x;
  float acc0 = 0.f, acc1 = 0.f, acc2 = 0.f, acc3 = 0.f;
  for (int k = 0; k < DIM; ++k) {
    float m = mlp[(size_t)k * DIM + j];          // coalesced
    const float* xr = &Xp[(size_t)k * NEXP + i0]; // uniform -> s_load
    acc0 = fmaf(xr[0], m, acc0);
    acc1 = fmaf(xr[1], m, acc1);
    acc2 = fmaf(xr[2], m, acc2);
    acc3 = fmaf(xr[3], m, acc3);
  }
  acc0 = fmaxf(acc0, 0.f); acc1 = fmaxf(acc1, 0.f);
  acc2 = fmaxf(acc2, 0.f); acc3 = fmaxf(acc3, 0.f);
  expT[(size_t)(i0 + 0) * DIM + j] = acc0;
  expT[(size_t)(i0 + 1) * DIM + j] = acc1;
  expT[(size_t)(i0 + 2) * DIM + j] = acc2;
  expT[(size_t)(i0 + 3) * DIM + j] = acc3;
  expTT[(size_t)j * NEXP + i0 + 0] = acc0;
  expTT[(size_t)j * NEXP + i0 + 1] = acc1;
  expTT[(size_t)j * NEXP + i0 + 2] = acc2;
  expTT[(size_t)j * NEXP + i0 + 3] = acc3;
}

// W01[i][d] = sum_k W0[i][k] * W1[k][d]
__global__ __launch_bounds__(256) void k_W01(const float* __restrict__ W0,
                                             const float* __restrict__ W1,
                                             float* __restrict__ W01) {
  int i = blockIdx.x;
  int d = threadIdx.x;
  float acc = 0.f;
#pragma unroll 4
  for (int k = 0; k < DG; ++k)
    acc = fmaf(W0[i * DG + k], W1[k * DG + d], acc);
  W01[i * DG + d] = acc;
}

// w3p[i] = dot(W3 row i, pw) — one block per i, wave reduce (was 1-block serial: 195us!)
__global__ __launch_bounds__(256) void k_w3p(const float* __restrict__ W3,
                                             const float* __restrict__ pw,
                                             float* __restrict__ w3p) {
  __shared__ float red[4];
  int i = blockIdx.x;
  int tid = threadIdx.x, lane = tid & 63, w = tid >> 6;
  const float* r = &W3[(size_t)i * DIM];
  float s = r[tid] * pw[tid]
          + r[tid + 256] * pw[tid + 256]
          + r[tid + 512] * pw[tid + 512]
          + r[tid + 768] * pw[tid + 768];
#pragma unroll
  for (int off = 32; off > 0; off >>= 1)
    s += __shfl_down(s, off, 64);
  if (lane == 0) red[w] = s;
  __syncthreads();
  if (tid == 0) w3p[i] = red[0] + red[1] + red[2] + red[3];
}

// D[i][j] = dot(exp_i, exp_j); 4-way k-split per block + LDS reduce
__global__ __launch_bounds__(256) void k_cos(const float* __restrict__ expTT,
                                             float* __restrict__ D) {
  __shared__ float part[4][NEXP];
  int i = blockIdx.x;
  int tid = threadIdx.x;
  int j = tid & 63, qd = tid >> 6;
  float acc = 0.f;
  int d0 = qd * 256;
  for (int d = d0; d < d0 + 256; ++d) {
    float ei = expTT[(size_t)d * NEXP + i];   // uniform -> s_load
    float ej = expTT[(size_t)d * NEXP + j];   // coalesced 256B
    acc = fmaf(ei, ej, acc);
  }
  part[qd][j] = acc;
  __syncthreads();
  if (tid < NEXP)
    D[i * NEXP + tid] = part[0][tid] + part[1][tid] + part[2][tid] + part[3][tid];
}

// Build normalized adjacency Ahat [65][65] and q = Ahat @ a0
__global__ __launch_bounds__(256) void k_buildA(const float* __restrict__ D,
                                                float* __restrict__ Ahat,
                                                float* __restrict__ q) {
  __shared__ float nrm[NEXP];
  __shared__ float Ar[NN][NN];
  __shared__ float Al[NN][NN];
  __shared__ float dd[NN];
  __shared__ float a0[NN];
  int tid = threadIdx.x;
  if (tid < NEXP) nrm[tid] = fmaxf(sqrtf(D[tid * NEXP + tid]), 1e-8f);
  __syncthreads();
  for (int e = tid; e < NN * NN; e += 256) {
    int n = e / NN, m = e - n * NN;
    float v = 0.f;
    if (n == m) v = 1.f;                              // self loop
    else if (m == NEXP) v = (n < NEXP) ? 1.f : 0.f;   // token -> each expert
    else if (n < NEXP && m < n) {                     // edge m->n for m<n
      float c = D[m * NEXP + n] / (nrm[m] * nrm[n]);
      v = (c > THR_EDGE) ? 1.f : 0.f;
    }
    Ar[n][m] = v;
  }
  __syncthreads();
  if (tid < NN) {
    float s = 0.f;
    for (int m = 0; m < NN; ++m) s += Ar[tid][m];
    dd[tid] = 1.0f / sqrtf(s);
  }
  __syncthreads();
  for (int e = tid; e < NN * NN; e += 256) {
    int n = e / NN, m = e - n * NN;
    float v = Ar[n][m] * dd[n] * dd[m];
    Al[n][m] = v;
    Ahat[e] = v;
  }
  __syncthreads();
  if (tid < NN) a0[tid] = Al[tid][NEXP];
  __syncthreads();
  if (tid < NN) {
    float s = 0.f;
    for (int m = 0; m < NN; ++m) s = fmaf(Al[tid][m], a0[m], s);
    q[tid] = s;
  }
}

// expW[m][d] = sum_k expT[m][k] * W0[k][d]
__global__ __launch_bounds__(256) void k_expW(const float* __restrict__ expT,
                                              const float* __restrict__ W0,
                                              float* __restrict__ expW) {
  int m = blockIdx.x, d = threadIdx.x;
  float acc = 0.f;
#pragma unroll 4
  for (int k = 0; k < DIM; ++k)
    acc = fmaf(expT[m * DIM + k], W0[k * DG + d], acc);
  expW[m * DG + d] = acc;
}

// CW1[n][d] = ((Ahat[:, :64] @ expW) @ W1)[n][d]
__global__ __launch_bounds__(256) void k_CW1(const float* __restrict__ Ahat,
                                             const float* __restrict__ expW,
                                             const float* __restrict__ W1,
                                             float* __restrict__ CW1) {
  __shared__ float c0[DG];
  int n = blockIdx.x, d = threadIdx.x;
  float acc = 0.f;
  for (int m = 0; m < NEXP; ++m)
    acc = fmaf(Ahat[n * NN + m], expW[m * DG + d], acc);
  c0[d] = acc;
  __syncthreads();
  float b = 0.f;
#pragma unroll 4
  for (int k = 0; k < DG; ++k)
    b = fmaf(c0[k], W1[k * DG + d], b);
  CW1[n * DG + d] = b;
}

// P[n][d] = (Ahat @ CW1)[n][d]
__global__ __launch_bounds__(256) void k_P(const float* __restrict__ Ahat,
                                           const float* __restrict__ CW1,
                                           float* __restrict__ P) {
  int n = blockIdx.x, d = threadIdx.x;
  float acc = 0.f;
  for (int m = 0; m < NN; ++m)
    acc = fmaf(Ahat[n * NN + m], CW1[m * DG + d], acc);
  P[n * DG + d] = acc;
}

// ---------------- fp32 tiled GEMM (64x64 tile, 4x4 micro) ----------------
template <bool RELU>
__global__ __launch_bounds__(256) void k_gemm(const float* __restrict__ A,
                                              const float* __restrict__ B,
                                              float* __restrict__ C,
                                              int M, int N, int K) {
  __shared__ float As[64][17];
  __shared__ float Bs[16][64];
  int tid = threadIdx.x;
  int tx = tid & 15, ty = tid >> 4;
  int bm0 = blockIdx.y * 64, bn0 = blockIdx.x * 64;
  int ar = tid >> 2, ac = (tid & 3) * 4;
  int brow = tid >> 4, bcol = (tid & 15) * 4;
  float acc[4][4] = {};
  for (int k0 = 0; k0 < K; k0 += 16) {
    float4 av = *(const float4*)&A[(size_t)(bm0 + ar) * K + k0 + ac];
    float4 bv = *(const float4*)&B[(size_t)(k0 + brow) * N + bn0 + bcol];
    As[ar][ac + 0] = av.x; As[ar][ac + 1] = av.y;
    As[ar][ac + 2] = av.z; As[ar][ac + 3] = av.w;
    *(float4*)&Bs[brow][bcol] = bv;
    __syncthreads();
#pragma unroll
    for (int kk = 0; kk < 16; ++kk) {
      float a0 = As[ty * 4 + 0][kk], a1 = As[ty * 4 + 1][kk];
      float a2 = As[ty * 4 + 2][kk], a3 = As[ty * 4 + 3][kk];
      float4 b = *(const float4*)&Bs[kk][tx * 4];
      acc[0][0] = fmaf(a0, b.x, acc[0][0]); acc[0][1] = fmaf(a0, b.y, acc[0][1]);
      acc[0][2] = fmaf(a0, b.z, acc[0][2]); acc[0][3] = fmaf(a0, b.w, acc[0][3]);
      acc[1][0] = fmaf(a1, b.x, acc[1][0]); acc[1][1] = fmaf(a1, b.y, acc[1][1]);
      acc[1][2] = fmaf(a1, b.z, acc[1][2]); acc[1][3] = fmaf(a1, b.w, acc[1][3]);
      acc[2][0] = fmaf(a2, b.x, acc[2][0]); acc[2][1] = fmaf(a2, b.y, acc[2][1]);
      acc[2][2] = fmaf(a2, b.z, acc[2][2]); acc[2][3] = fmaf(a2, b.w, acc[2][3]);
      acc[3][0] = fmaf(a3, b.x, acc[3][0]); acc[3][1] = fmaf(a3, b.y, acc[3][1]);
      acc[3][2] = fmaf(a3, b.z, acc[3][2]); acc[3][3] = fmaf(a3, b.w, acc[3][3]);
    }
    __syncthreads();
  }
#pragma unroll
  for (int i = 0; i < 4; ++i) {
    float4 v;
    v.x = acc[i][0]; v.y = acc[i][1]; v.z = acc[i][2]; v.w = acc[i][3];
    if (RELU) {
      v.x = fmaxf(v.x, 0.f); v.y = fmaxf(v.y, 0.f);
      v.z = fmaxf(v.z, 0.f); v.w = fmaxf(v.w, 0.f);
    }
    *(float4*)&C[(size_t)(bm0 + ty * 4 + i) * N + bn0 + tx * 4] = v;
  }
}

// ---------------- k_mix: G[nn][t][k] = sum_m Ahat[n0+nn][m] * R[t][m][k] ----------------
// R computed once per thread (not per n): r[m] = relu(P[m][k] + q[m]*V[t][k])
__global__ __launch_bounds__(256) void k_mix(const float* __restrict__ V,
                                             const float* __restrict__ P,
                                             const float* __restrict__ Ahat,
                                             const float* __restrict__ q,
                                             float* __restrict__ Gc,
                                             int n0, int nch) {
  int t = blockIdx.x;
  int k = threadIdx.x;
  float v = V[(size_t)t * DG + k];
  float r[NN];
#pragma unroll
  for (int m = 0; m < NN; ++m)
    r[m] = fmaxf(fmaf(q[m], v, P[m * DG + k]), 0.f);
  for (int nn = 0; nn < nch; ++nn) {
    const float* arow = &Ahat[(size_t)(n0 + nn) * NN];  // uniform -> s_loads
    float acc = 0.f;
#pragma unroll
    for (int m = 0; m < NN; ++m)
      acc = fmaf(arow[m], r[m], acc);
    Gc[((size_t)nn * T_TOK + t) * DG + k] = acc;
  }
}

// ---------------- k_zgemm: s2T[t][n] = sum_d relu((G[n,t]@W2)[d]) * w3p[d] ----------------
// Block = (t-tile of 128, one chunk-local n). Lane owns t=lane and t=lane+64,
// 64 d's per wave (wave w -> d in [w*64, w*64+64)). A from LDS (pad 37 -> 2-way free),
// B (W2 row) via readfirstlane-uniform pointer -> SMEM s_loads (no LDS, no VMEM).
#define ZTT 128
__global__ __launch_bounds__(256, 3) void k_zgemm(const float* __restrict__ Gc,
                                                  const float* __restrict__ W2,
                                                  const float* __restrict__ w3p,
                                                  float* __restrict__ s2T,
                                                  int n0) {
  __shared__ float As[ZTT][37];
  int tid = threadIdx.x;
  int ny = blockIdx.y;
  int t0 = blockIdx.x * ZTT;
  int lane = tid & 63, w = tid >> 6;
  int wofs = __builtin_amdgcn_readfirstlane(w * 64);

  float acc0[64], acc1[64];
#pragma unroll
  for (int j = 0; j < 64; ++j) { acc0[j] = 0.f; acc1[j] = 0.f; }

  const float* Abase = Gc + ((size_t)ny * T_TOK + t0) * DG;

  for (int k0 = 0; k0 < DG; k0 += 32) {
    // stage A: 128 rows x 32 cols
    {
      int r = tid >> 1, c = (tid & 1) * 16;
      const float* src = Abase + (size_t)r * DG + k0 + c;
      float4 x0 = *(const float4*)(src + 0);
      float4 x1 = *(const float4*)(src + 4);
      float4 x2 = *(const float4*)(src + 8);
      float4 x3 = *(const float4*)(src + 12);
      float* dst = &As[r][c];
      dst[0] = x0.x; dst[1] = x0.y; dst[2] = x0.z; dst[3] = x0.w;
      dst[4] = x1.x; dst[5] = x1.y; dst[6] = x1.z; dst[7] = x1.w;
      dst[8] = x2.x; dst[9] = x2.y; dst[10] = x2.z; dst[11] = x2.w;
      dst[12] = x3.x; dst[13] = x3.y; dst[14] = x3.z; dst[15] = x3.w;
    }
    __syncthreads();
#pragma unroll 2
    for (int kk = 0; kk < 32; ++kk) {
      float a0 = As[lane][kk];
      float a1 = As[lane + 64][kk];
      const float* brow = &W2[(size_t)(k0 + kk) * DG + wofs];  // uniform -> s_load
#pragma unroll
      for (int j = 0; j < 64; ++j) {
        float b = brow[j];
        acc0[j] = fmaf(a0, b, acc0[j]);
        acc1[j] = fmaf(a1, b, acc1[j]);
      }
    }
    __syncthreads();
  }

  // epilogue: relu -> *w3p -> reduce over d (64 per wave, then 4 waves)
  const float* wpr = &w3p[wofs];   // uniform
  float part0 = 0.f, part1 = 0.f;
#pragma unroll
  for (int j = 0; j < 64; ++j) {
    float wpj = wpr[j];
    part0 = fmaf(fmaxf(acc0[j], 0.f), wpj, part0);
    part1 = fmaf(fmaxf(acc1[j], 0.f), wpj, part1);
  }
  float* red = &As[0][0];          // reuse As (all reads done at last barrier)
  red[w * ZTT + lane] = part0;
  red[w * ZTT + 64 + lane] = part1;
  __syncthreads();
  if (tid < ZTT) {
    float s = red[tid] + red[ZTT + tid] + red[2 * ZTT + tid] + red[3 * ZTT + tid];
    s2T[(size_t)(t0 + tid) * NN + (n0 + ny)] = s;
  }
}

// ---------------- final: scores[t][j] = sum_m Ahat[j][m]*s2T[t][m]; softmax ----------------
__global__ __launch_bounds__(64) void k_final(const float* __restrict__ s2T,
                                              const float* __restrict__ Ahat,
                                              float* __restrict__ out) {
  __shared__ float s2l[NN];
  int t = blockIdx.x;
  int j = threadIdx.x;
  s2l[j] = s2T[(size_t)t * NN + j];
  if (j == 0) s2l[NEXP] = s2T[(size_t)t * NN + NEXP];
  __syncthreads();
  float sc = 0.f;
  for (int m = 0; m < NN; ++m)
    sc = fmaf(Ahat[j * NN + m], s2l[m], sc);
  float mx = sc;
#pragma unroll
  for (int off = 32; off > 0; off >>= 1)
    mx = fmaxf(mx, __shfl_xor(mx, off, 64));
  float e = expf(sc - mx);
  float sum = e;
#pragma unroll
  for (int off = 32; off > 0; off >>= 1)
    sum += __shfl_xor(sum, off, 64);
  out[(size_t)t * NEXP + j] = e / sum;
}

// ---------------- launch ----------------
extern "C" void kernel_launch(void* const* d_in, const int* in_sizes, int n_in,
                              void* d_out, int out_size, void* d_ws, size_t ws_size,
                              hipStream_t stream) {
  (void)in_sizes; (void)n_in; (void)out_size; (void)ws_size;
  const float* x   = (const float*)d_in[0];
  const float* Xp  = (const float*)d_in[1];
  const float* mlp = (const float*)d_in[2];
  const float* W0  = (const float*)d_in[3];
  const float* W1  = (const float*)d_in[4];
  const float* W2  = (const float*)d_in[5];
  const float* W3  = (const float*)d_in[6];
  const float* pw  = (const float*)d_in[7];
  float* out = (float*)d_out;
  float* ws = (float*)d_ws;

  // workspace layout (floats), total ~20.5M floats (~82 MB)
  float* expT  = ws + 0;         // 65536
  float* expTT = ws + 65536;     // 65536
  float* W01   = ws + 131072;    // 262144
  float* w3p   = ws + 393216;    // 256
  float* D     = ws + 393472;    // 4096
  float* Ahat  = ws + 397568;    // 4225 (+pad)
  float* q     = ws + 401808;    // 65 (+pad)
  float* expW  = ws + 401888;    // 16384
  float* CW1   = ws + 418272;    // 16640
  float* P     = ws + 434912;    // 16640
  float* s2T   = ws + 451552;    // 2048*65 = 133120
  float* XT    = ws + 584672;    // 2048*1024
  float* V     = ws + 2681824;   // 2048*256
  float* Gc    = ws + 3206112;   // 33*2048*256 = 17301504

  k_expT<<<dim3(4, 16), dim3(256), 0, stream>>>(Xp, mlp, expT, expTT);
  k_W01<<<dim3(1024), dim3(256), 0, stream>>>(W0, W1, W01);
  k_w3p<<<dim3(256), dim3(256), 0, stream>>>(W3, pw, w3p);
  k_cos<<<dim3(64), dim3(256), 0, stream>>>(expTT, D);
  k_buildA<<<dim3(1), dim3(256), 0, stream>>>(D, Ahat, q);
  k_expW<<<dim3(64), dim3(256), 0, stream>>>(expT, W0, expW);
  k_CW1<<<dim3(65), dim3(256), 0, stream>>>(Ahat, expW, W1, CW1);
  k_P<<<dim3(65), dim3(256), 0, stream>>>(Ahat, CW1, P);
  // XT = relu(x @ mlp_w)   [2048,1024]
  k_gemm<true><<<dim3(16, 32), dim3(256), 0, stream>>>(x, mlp, XT, 2048, 1024, 1024);
  // V = XT @ W01           [2048,256]
  k_gemm<false><<<dim3(4, 32), dim3(256), 0, stream>>>(XT, W01, V, 2048, 256, 1024);
  // chunked: G = Ahat-mix of R, then s2 = reduce(relu(G@W2)*w3p)
  k_mix<<<dim3(T_TOK), dim3(256), 0, stream>>>(V, P, Ahat, q, Gc, 0, 33);
  k_zgemm<<<dim3(16, 33), dim3(256), 0, stream>>>(Gc, W2, w3p, s2T, 0);
  k_mix<<<dim3(T_TOK), dim3(256), 0, stream>>>(V, P, Ahat, q, Gc, 33, 32);
  k_zgemm<<<dim3(16, 32), dim3(256), 0, stream>>>(Gc, W2, w3p, s2T, 33);
  // scores + softmax -> out [2048,64]
  k_final<<<dim3(T_TOK), dim3(64), 0, stream>>>(s2T, Ahat, out);
}

// Round 8
// 683.952 us; speedup vs baseline: 1.7508x; 1.0929x over previous
//
#include <hip/hip_runtime.h>
#include <hip/hip_bf16.h>
#include <math.h>

#define DIM 1024
#define NEXP 64
#define NN 65
#define DG 256
#define T_TOK 2048
#define THR_EDGE 0.5f

typedef __attribute__((ext_vector_type(8))) short bf16x8;
typedef __attribute__((ext_vector_type(4))) float f32x4;
typedef unsigned short ushort_t;

// RNE float->bf16 (raw ushort) and back
static __device__ __forceinline__ ushort_t f2bf(float x) {
  unsigned u = __float_as_uint(x);
  unsigned r = (u + 0x7FFFu + ((u >> 16) & 1u)) >> 16;
  return (ushort_t)r;
}
static __device__ __forceinline__ float bf2f(ushort_t h) {
  return __uint_as_float(((unsigned)h) << 16);
}

// ---------------- setup kernels ----------------

// expT[i][j] = relu(sum_k Xp[k][i] * mlp[k][j]); also expTT[j][i] for k_cos.
__global__ __launch_bounds__(256) void k_expT(const float* __restrict__ Xp,
                                              const float* __restrict__ mlp,
                                              float* __restrict__ expT,
                                              float* __restrict__ expTT) {
  int i0 = blockIdx.y * 4;
  int j = blockIdx.x * 256 + threadIdx.x;
  float acc0 = 0.f, acc1 = 0.f, acc2 = 0.f, acc3 = 0.f;
  for (int k = 0; k < DIM; ++k) {
    float m = mlp[(size_t)k * DIM + j];
    const float* xr = &Xp[(size_t)k * NEXP + i0];
    acc0 = fmaf(xr[0], m, acc0);
    acc1 = fmaf(xr[1], m, acc1);
    acc2 = fmaf(xr[2], m, acc2);
    acc3 = fmaf(xr[3], m, acc3);
  }
  acc0 = fmaxf(acc0, 0.f); acc1 = fmaxf(acc1, 0.f);
  acc2 = fmaxf(acc2, 0.f); acc3 = fmaxf(acc3, 0.f);
  expT[(size_t)(i0 + 0) * DIM + j] = acc0;
  expT[(size_t)(i0 + 1) * DIM + j] = acc1;
  expT[(size_t)(i0 + 2) * DIM + j] = acc2;
  expT[(size_t)(i0 + 3) * DIM + j] = acc3;
  expTT[(size_t)j * NEXP + i0 + 0] = acc0;
  expTT[(size_t)j * NEXP + i0 + 1] = acc1;
  expTT[(size_t)j * NEXP + i0 + 2] = acc2;
  expTT[(size_t)j * NEXP + i0 + 3] = acc3;
}

// W01[i][d] = sum_k W0[i][k] * W1[k][d]
__global__ __launch_bounds__(256) void k_W01(const float* __restrict__ W0,
                                             const float* __restrict__ W1,
                                             float* __restrict__ W01) {
  int i = blockIdx.x;
  int d = threadIdx.x;
  float acc = 0.f;
#pragma unroll 4
  for (int k = 0; k < DG; ++k)
    acc = fmaf(W0[i * DG + k], W1[k * DG + d], acc);
  W01[i * DG + d] = acc;
}

// w3p[i] = dot(W3 row i, pw) — one block per i
__global__ __launch_bounds__(256) void k_w3p(const float* __restrict__ W3,
                                             const float* __restrict__ pw,
                                             float* __restrict__ w3p) {
  __shared__ float red[4];
  int i = blockIdx.x;
  int tid = threadIdx.x, lane = tid & 63, w = tid >> 6;
  const float* r = &W3[(size_t)i * DIM];
  float s = r[tid] * pw[tid]
          + r[tid + 256] * pw[tid + 256]
          + r[tid + 512] * pw[tid + 512]
          + r[tid + 768] * pw[tid + 768];
#pragma unroll
  for (int off = 32; off > 0; off >>= 1)
    s += __shfl_down(s, off, 64);
  if (lane == 0) red[w] = s;
  __syncthreads();
  if (tid == 0) w3p[i] = red[0] + red[1] + red[2] + red[3];
}

// D[i][j] = dot(exp_i, exp_j); 4-way k-split per block + LDS reduce
__global__ __launch_bounds__(256) void k_cos(const float* __restrict__ expTT,
                                             float* __restrict__ D) {
  __shared__ float part[4][NEXP];
  int i = blockIdx.x;
  int tid = threadIdx.x;
  int j = tid & 63, qd = tid >> 6;
  float acc = 0.f;
  int d0 = qd * 256;
  for (int d = d0; d < d0 + 256; ++d) {
    float ei = expTT[(size_t)d * NEXP + i];
    float ej = expTT[(size_t)d * NEXP + j];
    acc = fmaf(ei, ej, acc);
  }
  part[qd][j] = acc;
  __syncthreads();
  if (tid < NEXP)
    D[i * NEXP + tid] = part[0][tid] + part[1][tid] + part[2][tid] + part[3][tid];
}

// Split W2 into bf16 hi/lo planes in MFMA-frag-major layout:
// idx(k,d) = ((dt*8 + ks)*64 + kg*16 + c)*8 + j
//   dt=d>>4, c=d&15, ks=k>>5, kg=(k>>3)&3, j=k&7
__global__ __launch_bounds__(256) void k_splitW2(const float* __restrict__ W2,
                                                 ushort_t* __restrict__ Wh,
                                                 ushort_t* __restrict__ Wl) {
  int k = blockIdx.x;
  int d = threadIdx.x;
  float w = W2[(size_t)k * DG + d];
  ushort_t h = f2bf(w);
  ushort_t l = f2bf(w - bf2f(h));
  int dt = d >> 4, c = d & 15, ks = k >> 5, kg = (k >> 3) & 3, j = k & 7;
  int idx = (((dt * 8 + ks) * 64) + kg * 16 + c) * 8 + j;
  Wh[idx] = h;
  Wl[idx] = l;
}

// Build normalized adjacency Ahat [65][65] and q = Ahat @ a0
__global__ __launch_bounds__(256) void k_buildA(const float* __restrict__ D,
                                                float* __restrict__ Ahat,
                                                float* __restrict__ q) {
  __shared__ float nrm[NEXP];
  __shared__ float Ar[NN][NN];
  __shared__ float Al[NN][NN];
  __shared__ float dd[NN];
  __shared__ float a0[NN];
  int tid = threadIdx.x;
  if (tid < NEXP) nrm[tid] = fmaxf(sqrtf(D[tid * NEXP + tid]), 1e-8f);
  __syncthreads();
  for (int e = tid; e < NN * NN; e += 256) {
    int n = e / NN, m = e - n * NN;
    float v = 0.f;
    if (n == m) v = 1.f;                              // self loop
    else if (m == NEXP) v = (n < NEXP) ? 1.f : 0.f;   // token -> each expert
    else if (n < NEXP && m < n) {                     // edge m->n for m<n
      float c = D[m * NEXP + n] / (nrm[m] * nrm[n]);
      v = (c > THR_EDGE) ? 1.f : 0.f;
    }
    Ar[n][m] = v;
  }
  __syncthreads();
  if (tid < NN) {
    float s = 0.f;
    for (int m = 0; m < NN; ++m) s += Ar[tid][m];
    dd[tid] = 1.0f / sqrtf(s);
  }
  __syncthreads();
  for (int e = tid; e < NN * NN; e += 256) {
    int n = e / NN, m = e - n * NN;
    float v = Ar[n][m] * dd[n] * dd[m];
    Al[n][m] = v;
    Ahat[e] = v;
  }
  __syncthreads();
  if (tid < NN) a0[tid] = Al[tid][NEXP];
  __syncthreads();
  if (tid < NN) {
    float s = 0.f;
    for (int m = 0; m < NN; ++m) s = fmaf(Al[tid][m], a0[m], s);
    q[tid] = s;
  }
}

// expW[m][d] = sum_k expT[m][k] * W0[k][d]
__global__ __launch_bounds__(256) void k_expW(const float* __restrict__ expT,
                                              const float* __restrict__ W0,
                                              float* __restrict__ expW) {
  int m = blockIdx.x, d = threadIdx.x;
  float acc = 0.f;
#pragma unroll 4
  for (int k = 0; k < DIM; ++k)
    acc = fmaf(expT[m * DIM + k], W0[k * DG + d], acc);
  expW[m * DG + d] = acc;
}

// CW1[n][d] = ((Ahat[:, :64] @ expW) @ W1)[n][d]
__global__ __launch_bounds__(256) void k_CW1(const float* __restrict__ Ahat,
                                             const float* __restrict__ expW,
                                             const float* __restrict__ W1,
                                             float* __restrict__ CW1) {
  __shared__ float c0[DG];
  int n = blockIdx.x, d = threadIdx.x;
  float acc = 0.f;
  for (int m = 0; m < NEXP; ++m)
    acc = fmaf(Ahat[n * NN + m], expW[m * DG + d], acc);
  c0[d] = acc;
  __syncthreads();
  float b = 0.f;
#pragma unroll 4
  for (int k = 0; k < DG; ++k)
    b = fmaf(c0[k], W1[k * DG + d], b);
  CW1[n * DG + d] = b;
}

// P[n][d] = (Ahat @ CW1)[n][d]
__global__ __launch_bounds__(256) void k_P(const float* __restrict__ Ahat,
                                           const float* __restrict__ CW1,
                                           float* __restrict__ P) {
  int n = blockIdx.x, d = threadIdx.x;
  float acc = 0.f;
  for (int m = 0; m < NN; ++m)
    acc = fmaf(Ahat[n * NN + m], CW1[m * DG + d], acc);
  P[n * DG + d] = acc;
}

// ---------------- fp32 tiled GEMM (64x64 tile, 4x4 micro) ----------------
template <bool RELU>
__global__ __launch_bounds__(256) void k_gemm(const float* __restrict__ A,
                                              const float* __restrict__ B,
                                              float* __restrict__ C,
                                              int M, int N, int K) {
  __shared__ float As[64][17];
  __shared__ float Bs[16][64];
  int tid = threadIdx.x;
  int tx = tid & 15, ty = tid >> 4;
  int bm0 = blockIdx.y * 64, bn0 = blockIdx.x * 64;
  int ar = tid >> 2, ac = (tid & 3) * 4;
  int brow = tid >> 4, bcol = (tid & 15) * 4;
  float acc[4][4] = {};
  for (int k0 = 0; k0 < K; k0 += 16) {
    float4 av = *(const float4*)&A[(size_t)(bm0 + ar) * K + k0 + ac];
    float4 bv = *(const float4*)&B[(size_t)(k0 + brow) * N + bn0 + bcol];
    As[ar][ac + 0] = av.x; As[ar][ac + 1] = av.y;
    As[ar][ac + 2] = av.z; As[ar][ac + 3] = av.w;
    *(float4*)&Bs[brow][bcol] = bv;
    __syncthreads();
#pragma unroll
    for (int kk = 0; kk < 16; ++kk) {
      float a0 = As[ty * 4 + 0][kk], a1 = As[ty * 4 + 1][kk];
      float a2 = As[ty * 4 + 2][kk], a3 = As[ty * 4 + 3][kk];
      float4 b = *(const float4*)&Bs[kk][tx * 4];
      acc[0][0] = fmaf(a0, b.x, acc[0][0]); acc[0][1] = fmaf(a0, b.y, acc[0][1]);
      acc[0][2] = fmaf(a0, b.z, acc[0][2]); acc[0][3] = fmaf(a0, b.w, acc[0][3]);
      acc[1][0] = fmaf(a1, b.x, acc[1][0]); acc[1][1] = fmaf(a1, b.y, acc[1][1]);
      acc[1][2] = fmaf(a1, b.z, acc[1][2]); acc[1][3] = fmaf(a1, b.w, acc[1][3]);
      acc[2][0] = fmaf(a2, b.x, acc[2][0]); acc[2][1] = fmaf(a2, b.y, acc[2][1]);
      acc[2][2] = fmaf(a2, b.z, acc[2][2]); acc[2][3] = fmaf(a2, b.w, acc[2][3]);
      acc[3][0] = fmaf(a3, b.x, acc[3][0]); acc[3][1] = fmaf(a3, b.y, acc[3][1]);
      acc[3][2] = fmaf(a3, b.z, acc[3][2]); acc[3][3] = fmaf(a3, b.w, acc[3][3]);
    }
    __syncthreads();
  }
#pragma unroll
  for (int i = 0; i < 4; ++i) {
    float4 v;
    v.x = acc[i][0]; v.y = acc[i][1]; v.z = acc[i][2]; v.w = acc[i][3];
    if (RELU) {
      v.x = fmaxf(v.x, 0.f); v.y = fmaxf(v.y, 0.f);
      v.z = fmaxf(v.z, 0.f); v.w = fmaxf(v.w, 0.f);
    }
    *(float4*)&C[(size_t)(bm0 + ty * 4 + i) * N + bn0 + tx * 4] = v;
  }
}

// ---------------- k_mix: G[nn][t][k] = sum_m Ahat[n0+nn][m]*relu(P[m][k]+q[m]V[t][k]) ----------------
// Emits G as bf16 hi/lo planes (split-bf16 for the MFMA consumer).
__global__ __launch_bounds__(256) void k_mix(const float* __restrict__ V,
                                             const float* __restrict__ P,
                                             const float* __restrict__ Ahat,
                                             const float* __restrict__ q,
                                             ushort_t* __restrict__ Gh,
                                             ushort_t* __restrict__ Gl,
                                             int n0, int nch) {
  int t = blockIdx.x;
  int k = threadIdx.x;
  float v = V[(size_t)t * DG + k];
  float r[NN];
#pragma unroll
  for (int m = 0; m < NN; ++m)
    r[m] = fmaxf(fmaf(q[m], v, P[m * DG + k]), 0.f);
  for (int nn = 0; nn < nch; ++nn) {
    const float* arow = &Ahat[(size_t)(n0 + nn) * NN];  // uniform -> s_loads
    float acc = 0.f;
#pragma unroll
    for (int m = 0; m < NN; ++m)
      acc = fmaf(arow[m], r[m], acc);
    size_t idx = ((size_t)nn * T_TOK + t) * DG + k;
    ushort_t h = f2bf(acc);
    Gh[idx] = h;
    Gl[idx] = f2bf(acc - bf2f(h));
  }
}

// ---------------- k_zgemm (MFMA split-bf16): s2T[t][n] = sum_d relu((G@W2)[d])*w3p[d] ----
// Block = 64 tokens x one chunk-local n; 4 waves, wave owns 16 t-rows x 256 d.
// A-frags (G hi/lo rows) register-resident; B-frags from frag-major W2f (coalesced,
// L2-broadcast). 4 MFMA per (dt,ks): hh + lh + hl + ll. Epilogue: relu*w3p, 16-lane
// shfl reduce -> s2T.
__global__ __launch_bounds__(256, 2) void k_zgemm(const ushort_t* __restrict__ Gh,
                                                  const ushort_t* __restrict__ Gl,
                                                  const ushort_t* __restrict__ Wh,
                                                  const ushort_t* __restrict__ Wl,
                                                  const float* __restrict__ w3p,
                                                  float* __restrict__ s2T,
                                                  int n0) {
  int tid = threadIdx.x, lane = tid & 63, w = tid >> 6;
  int ny = blockIdx.y;
  int t0 = blockIdx.x * 64 + w * 16;      // wave's 16 token rows
  int row = lane & 15, kg = lane >> 4;    // A: row, k-group

  // A-frags: lane holds G[t0+row][ks*32 + kg*8 + j], j=0..7
  const ushort_t* Ah = Gh + ((size_t)ny * T_TOK + t0 + row) * DG + kg * 8;
  const ushort_t* Al = Gl + ((size_t)ny * T_TOK + t0 + row) * DG + kg * 8;
  bf16x8 ah[8], al[8];
#pragma unroll
  for (int ks = 0; ks < 8; ++ks) {
    ah[ks] = *(const bf16x8*)(Ah + ks * 32);
    al[ks] = *(const bf16x8*)(Al + ks * 32);
  }

  float wp[16];
#pragma unroll
  for (int dt = 0; dt < 16; ++dt) wp[dt] = w3p[dt * 16 + row];   // row == C col (lane&15)

  f32x4 acc[16];
#pragma unroll
  for (int dt = 0; dt < 16; ++dt) acc[dt] = (f32x4){0.f, 0.f, 0.f, 0.f};

#pragma unroll
  for (int dt = 0; dt < 16; ++dt) {
    const ushort_t* Bh = Wh + (size_t)dt * 4096 + lane * 8;
    const ushort_t* Bl = Wl + (size_t)dt * 4096 + lane * 8;
#pragma unroll
    for (int ks = 0; ks < 8; ++ks) {
      bf16x8 bh = *(const bf16x8*)(Bh + ks * 512);
      bf16x8 bl = *(const bf16x8*)(Bl + ks * 512);
      acc[dt] = __builtin_amdgcn_mfma_f32_16x16x32_bf16(ah[ks], bh, acc[dt], 0, 0, 0);
      acc[dt] = __builtin_amdgcn_mfma_f32_16x16x32_bf16(al[ks], bh, acc[dt], 0, 0, 0);
      acc[dt] = __builtin_amdgcn_mfma_f32_16x16x32_bf16(ah[ks], bl, acc[dt], 0, 0, 0);
      acc[dt] = __builtin_amdgcn_mfma_f32_16x16x32_bf16(al[ks], bl, acc[dt], 0, 0, 0);
    }
  }

  // epilogue: C[r][c] at col=lane&15, row(t) = t0 + kg*4 + r
  float v0 = 0.f, v1 = 0.f, v2 = 0.f, v3 = 0.f;
#pragma unroll
  for (int dt = 0; dt < 16; ++dt) {
    float wpd = wp[dt];
    v0 = fmaf(fmaxf(acc[dt][0], 0.f), wpd, v0);
    v1 = fmaf(fmaxf(acc[dt][1], 0.f), wpd, v1);
    v2 = fmaf(fmaxf(acc[dt][2], 0.f), wpd, v2);
    v3 = fmaf(fmaxf(acc[dt][3], 0.f), wpd, v3);
  }
#pragma unroll
  for (int off = 1; off < 16; off <<= 1) {
    v0 += __shfl_xor(v0, off, 64);
    v1 += __shfl_xor(v1, off, 64);
    v2 += __shfl_xor(v2, off, 64);
    v3 += __shfl_xor(v3, off, 64);
  }
  if (row == 0) {
    int t = t0 + kg * 4;
    int n = n0 + ny;
    s2T[(size_t)(t + 0) * NN + n] = v0;
    s2T[(size_t)(t + 1) * NN + n] = v1;
    s2T[(size_t)(t + 2) * NN + n] = v2;
    s2T[(size_t)(t + 3) * NN + n] = v3;
  }
}

// ---------------- final: scores[t][j] = sum_m Ahat[j][m]*s2T[t][m]; softmax ----------------
__global__ __launch_bounds__(64) void k_final(const float* __restrict__ s2T,
                                              const float* __restrict__ Ahat,
                                              float* __restrict__ out) {
  __shared__ float s2l[NN];
  int t = blockIdx.x;
  int j = threadIdx.x;
  s2l[j] = s2T[(size_t)t * NN + j];
  if (j == 0) s2l[NEXP] = s2T[(size_t)t * NN + NEXP];
  __syncthreads();
  float sc = 0.f;
  for (int m = 0; m < NN; ++m)
    sc = fmaf(Ahat[j * NN + m], s2l[m], sc);
  float mx = sc;
#pragma unroll
  for (int off = 32; off > 0; off >>= 1)
    mx = fmaxf(mx, __shfl_xor(mx, off, 64));
  float e = expf(sc - mx);
  float sum = e;
#pragma unroll
  for (int off = 32; off > 0; off >>= 1)
    sum += __shfl_xor(sum, off, 64);
  out[(size_t)t * NEXP + j] = e / sum;
}

// ---------------- launch ----------------
extern "C" void kernel_launch(void* const* d_in, const int* in_sizes, int n_in,
                              void* d_out, int out_size, void* d_ws, size_t ws_size,
                              hipStream_t stream) {
  (void)in_sizes; (void)n_in; (void)out_size; (void)ws_size;
  const float* x   = (const float*)d_in[0];
  const float* Xp  = (const float*)d_in[1];
  const float* mlp = (const float*)d_in[2];
  const float* W0  = (const float*)d_in[3];
  const float* W1  = (const float*)d_in[4];
  const float* W2  = (const float*)d_in[5];
  const float* W3  = (const float*)d_in[6];
  const float* pw  = (const float*)d_in[7];
  float* out = (float*)d_out;
  float* ws = (float*)d_ws;

  // workspace layout (floats), total 20,507,616 floats (~82 MB) — same as round 7
  float* expT  = ws + 0;         // 65536
  float* expTT = ws + 65536;     // 65536 (dead after k_cos -> reused for W2f)
  float* W01   = ws + 131072;    // 262144
  float* w3p   = ws + 393216;    // 256
  float* D     = ws + 393472;    // 4096
  float* Ahat  = ws + 397568;    // 4240
  float* q     = ws + 401808;    // 80
  float* expW  = ws + 401888;    // 16384
  float* CW1   = ws + 418272;    // 16640
  float* P     = ws + 434912;    // 16640
  float* s2T   = ws + 451552;    // 133120
  float* XT    = ws + 584672;    // 2097152
  float* V     = ws + 2681824;   // 524288
  ushort_t* W2f_h = (ushort_t*)(ws + 65536);          // 32768 fl (overlay expTT)
  ushort_t* W2f_l = (ushort_t*)(ws + 65536 + 32768);  // 32768 fl (overlay expTT)
  ushort_t* Gc_h  = (ushort_t*)(ws + 3206112);        // 33*2048*256 us = 8650752 fl
  ushort_t* Gc_l  = (ushort_t*)(ws + 3206112 + 8650752); // 8650752 fl

  k_expT<<<dim3(4, 16), dim3(256), 0, stream>>>(Xp, mlp, expT, expTT);
  k_W01<<<dim3(1024), dim3(256), 0, stream>>>(W0, W1, W01);
  k_w3p<<<dim3(256), dim3(256), 0, stream>>>(W3, pw, w3p);
  k_cos<<<dim3(64), dim3(256), 0, stream>>>(expTT, D);
  k_splitW2<<<dim3(256), dim3(256), 0, stream>>>(W2, W2f_h, W2f_l);  // after k_cos: expTT dead
  k_buildA<<<dim3(1), dim3(256), 0, stream>>>(D, Ahat, q);
  k_expW<<<dim3(64), dim3(256), 0, stream>>>(expT, W0, expW);
  k_CW1<<<dim3(65), dim3(256), 0, stream>>>(Ahat, expW, W1, CW1);
  k_P<<<dim3(65), dim3(256), 0, stream>>>(Ahat, CW1, P);
  // XT = relu(x @ mlp_w)   [2048,1024]
  k_gemm<true><<<dim3(16, 32), dim3(256), 0, stream>>>(x, mlp, XT, 2048, 1024, 1024);
  // V = XT @ W01           [2048,256]
  k_gemm<false><<<dim3(4, 32), dim3(256), 0, stream>>>(XT, W01, V, 2048, 256, 1024);
  // chunked: G (bf16 hi/lo) = Ahat-mix of R; s2 = reduce(relu(G@W2)*w3p) via MFMA
  k_mix<<<dim3(T_TOK), dim3(256), 0, stream>>>(V, P, Ahat, q, Gc_h, Gc_l, 0, 33);
  k_zgemm<<<dim3(32, 33), dim3(256), 0, stream>>>(Gc_h, Gc_l, W2f_h, W2f_l, w3p, s2T, 0);
  k_mix<<<dim3(T_TOK), dim3(256), 0, stream>>>(V, P, Ahat, q, Gc_h, Gc_l, 33, 32);
  k_zgemm<<<dim3(32, 32), dim3(256), 0, stream>>>(Gc_h, Gc_l, W2f_h, W2f_l, w3p, s2T, 33);
  // scores + softmax -> out [2048,64]
  k_final<<<dim3(T_TOK), dim3(64), 0, stream>>>(s2T, Ahat, out);
}

// Round 9
// 611.934 us; speedup vs baseline: 1.9568x; 1.1177x over previous
//
#include <hip/hip_runtime.h>
#include <hip/hip_bf16.h>
#include <math.h>

#define DIM 1024
#define NEXP 64
#define NN 65
#define DG 256
#define T_TOK 2048
#define THR_EDGE 0.5f

typedef __attribute__((ext_vector_type(8))) short bf16x8;
typedef __attribute__((ext_vector_type(4))) float f32x4;
typedef unsigned short ushort_t;
typedef __attribute__((ext_vector_type(8))) unsigned short us8;

// RNE float->bf16 (raw ushort) and back
static __device__ __forceinline__ ushort_t f2bf(float x) {
  unsigned u = __float_as_uint(x);
  unsigned r = (u + 0x7FFFu + ((u >> 16) & 1u)) >> 16;
  return (ushort_t)r;
}
static __device__ __forceinline__ float bf2f(ushort_t h) {
  return __uint_as_float(((unsigned)h) << 16);
}

// ---------------- setup kernels ----------------

// K-split expT partials: part[kc][i][j] = sum_{k in chunk} Xp[k][i]*mlp[k][j]
__global__ __launch_bounds__(256) void k_expT_ks(const float* __restrict__ Xp,
                                                 const float* __restrict__ mlp,
                                                 float* __restrict__ part) {
  int i0 = blockIdx.y * 4;
  int j = blockIdx.x * 256 + threadIdx.x;
  int k0 = blockIdx.z * 128;
  float acc0 = 0.f, acc1 = 0.f, acc2 = 0.f, acc3 = 0.f;
#pragma unroll 4
  for (int k = k0; k < k0 + 128; ++k) {
    float m = mlp[(size_t)k * DIM + j];            // coalesced
    const float* xr = &Xp[(size_t)k * NEXP + i0];  // uniform -> s_load
    acc0 = fmaf(xr[0], m, acc0);
    acc1 = fmaf(xr[1], m, acc1);
    acc2 = fmaf(xr[2], m, acc2);
    acc3 = fmaf(xr[3], m, acc3);
  }
  size_t base = ((size_t)blockIdx.z * NEXP + i0) * DIM + j;
  part[base + 0 * DIM] = acc0;
  part[base + 1 * DIM] = acc1;
  part[base + 2 * DIM] = acc2;
  part[base + 3 * DIM] = acc3;
}

// reduce partials: expT[i][j] = relu(sum_kc part), also expTT[j][i]
__global__ __launch_bounds__(256) void k_expT_red(const float* __restrict__ part,
                                                  float* __restrict__ expT,
                                                  float* __restrict__ expTT) {
  int e = blockIdx.x * 256 + threadIdx.x;   // 64K elems
  int i = e >> 10, j = e & 1023;
  float v = 0.f;
#pragma unroll
  for (int kc = 0; kc < 8; ++kc)
    v += part[(size_t)kc * (NEXP * DIM) + e];
  v = fmaxf(v, 0.f);
  expT[e] = v;
  expTT[(size_t)j * NEXP + i] = v;
}

// W01 = W0@W1, emitted directly as frag-major bf16 hi/lo (B-operand, K=1024,N=256)
__global__ __launch_bounds__(256) void k_W01(const float* __restrict__ W0,
                                             const float* __restrict__ W1,
                                             ushort_t* __restrict__ Bh,
                                             ushort_t* __restrict__ Bl) {
  int i = blockIdx.x;      // k-dim (1024)
  int d = threadIdx.x;     // n-dim (256)
  float acc = 0.f;
#pragma unroll 4
  for (int k = 0; k < DG; ++k)
    acc = fmaf(W0[i * DG + k], W1[k * DG + d], acc);
  int dt = d >> 4, c = d & 15, ks = i >> 5, kg = (i >> 3) & 3, j = i & 7;
  size_t idx = (((size_t)dt * 32 + ks) * 64 + kg * 16 + c) * 8 + j;
  ushort_t h = f2bf(acc);
  Bh[idx] = h;
  Bl[idx] = f2bf(acc - bf2f(h));
}

// w3p[i] = dot(W3 row i, pw) — one block per i
__global__ __launch_bounds__(256) void k_w3p(const float* __restrict__ W3,
                                             const float* __restrict__ pw,
                                             float* __restrict__ w3p) {
  __shared__ float red[4];
  int i = blockIdx.x;
  int tid = threadIdx.x, lane = tid & 63, w = tid >> 6;
  const float* r = &W3[(size_t)i * DIM];
  float s = r[tid] * pw[tid]
          + r[tid + 256] * pw[tid + 256]
          + r[tid + 512] * pw[tid + 512]
          + r[tid + 768] * pw[tid + 768];
#pragma unroll
  for (int off = 32; off > 0; off >>= 1)
    s += __shfl_down(s, off, 64);
  if (lane == 0) red[w] = s;
  __syncthreads();
  if (tid == 0) w3p[i] = red[0] + red[1] + red[2] + red[3];
}

// split x into bf16 hi/lo row-major planes (A-operand)
__global__ __launch_bounds__(256) void k_splitX(const float* __restrict__ X,
                                                ushort_t* __restrict__ Xh,
                                                ushort_t* __restrict__ Xl) {
  size_t base = ((size_t)blockIdx.x * 256 + threadIdx.x) * 8;
  us8 h, l;
#pragma unroll
  for (int u = 0; u < 8; ++u) {
    float v = X[base + u];
    ushort_t hh = f2bf(v);
    h[u] = hh;
    l[u] = f2bf(v - bf2f(hh));
  }
  *(us8*)(Xh + base) = h;
  *(us8*)(Xl + base) = l;
}

// split B [K][N] fp32 into frag-major bf16 hi/lo. thread = (k0 8-aligned, n)
__global__ __launch_bounds__(256) void k_splitB(const float* __restrict__ B,
                                                ushort_t* __restrict__ Bh,
                                                ushort_t* __restrict__ Bl,
                                                int K, int N) {
  int k0 = blockIdx.x * 8;
  int d = blockIdx.y * 256 + threadIdx.x;
  int KS = K >> 5;
  int dt = d >> 4, c = d & 15, ks = k0 >> 5, kg = (k0 >> 3) & 3;
  size_t idx = (((size_t)dt * KS + ks) * 64 + kg * 16 + c) * 8;
  us8 h, l;
#pragma unroll
  for (int j = 0; j < 8; ++j) {
    float v = B[(size_t)(k0 + j) * N + d];
    ushort_t hh = f2bf(v);
    h[j] = hh;
    l[j] = f2bf(v - bf2f(hh));
  }
  *(us8*)(Bh + idx) = h;
  *(us8*)(Bl + idx) = l;
}

// D[i][j] = dot(exp_i, exp_j); 4-way k-split per block + LDS reduce
__global__ __launch_bounds__(256) void k_cos(const float* __restrict__ expTT,
                                             float* __restrict__ D) {
  __shared__ float part[4][NEXP];
  int i = blockIdx.x;
  int tid = threadIdx.x;
  int j = tid & 63, qd = tid >> 6;
  float acc = 0.f;
  int d0 = qd * 256;
  for (int d = d0; d < d0 + 256; ++d) {
    float ei = expTT[(size_t)d * NEXP + i];
    float ej = expTT[(size_t)d * NEXP + j];
    acc = fmaf(ei, ej, acc);
  }
  part[qd][j] = acc;
  __syncthreads();
  if (tid < NEXP)
    D[i * NEXP + tid] = part[0][tid] + part[1][tid] + part[2][tid] + part[3][tid];
}

// Split W2 into bf16 hi/lo planes in MFMA-frag-major layout (K=256 -> KS=8)
__global__ __launch_bounds__(256) void k_splitW2(const float* __restrict__ W2,
                                                 ushort_t* __restrict__ Wh,
                                                 ushort_t* __restrict__ Wl) {
  int k = blockIdx.x;
  int d = threadIdx.x;
  float w = W2[(size_t)k * DG + d];
  ushort_t h = f2bf(w);
  ushort_t l = f2bf(w - bf2f(h));
  int dt = d >> 4, c = d & 15, ks = k >> 5, kg = (k >> 3) & 3, j = k & 7;
  int idx = (((dt * 8 + ks) * 64) + kg * 16 + c) * 8 + j;
  Wh[idx] = h;
  Wl[idx] = l;
}

// Build normalized adjacency Ahat [65][65] and q = Ahat @ a0
__global__ __launch_bounds__(256) void k_buildA(const float* __restrict__ D,
                                                float* __restrict__ Ahat,
                                                float* __restrict__ q) {
  __shared__ float nrm[NEXP];
  __shared__ float Ar[NN][NN];
  __shared__ float Al[NN][NN];
  __shared__ float dd[NN];
  __shared__ float a0[NN];
  int tid = threadIdx.x;
  if (tid < NEXP) nrm[tid] = fmaxf(sqrtf(D[tid * NEXP + tid]), 1e-8f);
  __syncthreads();
  for (int e = tid; e < NN * NN; e += 256) {
    int n = e / NN, m = e - n * NN;
    float v = 0.f;
    if (n == m) v = 1.f;                              // self loop
    else if (m == NEXP) v = (n < NEXP) ? 1.f : 0.f;   // token -> each expert
    else if (n < NEXP && m < n) {                     // edge m->n for m<n
      float c = D[m * NEXP + n] / (nrm[m] * nrm[n]);
      v = (c > THR_EDGE) ? 1.f : 0.f;
    }
    Ar[n][m] = v;
  }
  __syncthreads();
  if (tid < NN) {
    float s = 0.f;
    for (int m = 0; m < NN; ++m) s += Ar[tid][m];
    dd[tid] = 1.0f / sqrtf(s);
  }
  __syncthreads();
  for (int e = tid; e < NN * NN; e += 256) {
    int n = e / NN, m = e - n * NN;
    float v = Ar[n][m] * dd[n] * dd[m];
    Al[n][m] = v;
    Ahat[e] = v;
  }
  __syncthreads();
  if (tid < NN) a0[tid] = Al[tid][NEXP];
  __syncthreads();
  if (tid < NN) {
    float s = 0.f;
    for (int m = 0; m < NN; ++m) s = fmaf(Al[tid][m], a0[m], s);
    q[tid] = s;
  }
}

// expW[m][d] = sum_k expT[m][k] * W0[k][d]
__global__ __launch_bounds__(256) void k_expW(const float* __restrict__ expT,
                                              const float* __restrict__ W0,
                                              float* __restrict__ expW) {
  int m = blockIdx.x, d = threadIdx.x;
  float acc = 0.f;
#pragma unroll 4
  for (int k = 0; k < DIM; ++k)
    acc = fmaf(expT[m * DIM + k], W0[k * DG + d], acc);
  expW[m * DG + d] = acc;
}

// CW1[n][d] = ((Ahat[:, :64] @ expW) @ W1)[n][d]
__global__ __launch_bounds__(256) void k_CW1(const float* __restrict__ Ahat,
                                             const float* __restrict__ expW,
                                             const float* __restrict__ W1,
                                             float* __restrict__ CW1) {
  __shared__ float c0[DG];
  int n = blockIdx.x, d = threadIdx.x;
  float acc = 0.f;
  for (int m = 0; m < NEXP; ++m)
    acc = fmaf(Ahat[n * NN + m], expW[m * DG + d], acc);
  c0[d] = acc;
  __syncthreads();
  float b = 0.f;
#pragma unroll 4
  for (int k = 0; k < DG; ++k)
    b = fmaf(c0[k], W1[k * DG + d], b);
  CW1[n * DG + d] = b;
}

// P[n][d] = (Ahat @ CW1)[n][d]
__global__ __launch_bounds__(256) void k_P(const float* __restrict__ Ahat,
                                           const float* __restrict__ CW1,
                                           float* __restrict__ P) {
  int n = blockIdx.x, d = threadIdx.x;
  float acc = 0.f;
  for (int m = 0; m < NN; ++m)
    acc = fmaf(Ahat[n * NN + m], CW1[m * DG + d], acc);
  P[n * DG + d] = acc;
}

// ---------------- k_mgemm: MFMA split-bf16 GEMM C = [relu](A@B) ----------------
// A: [M][K] bf16 hi/lo row-major. B: frag-major hi/lo (k_splitB layout).
// Block: 64 rows x NT*16 cols, 4 waves (wave = 16 rows). Same fragment math as
// the verified k_zgemm: A lane holds row=lane&15, k=(lane>>4)*8+j; B lane holds
// col=lane&15, same k-group; C col=lane&15, row=(lane>>4)*4+reg.
template <int NT, bool RELU, bool OSPLIT>
__global__ __launch_bounds__(256) void k_mgemm(const ushort_t* __restrict__ Ah,
                                               const ushort_t* __restrict__ Al,
                                               const ushort_t* __restrict__ Bh,
                                               const ushort_t* __restrict__ Bl,
                                               float* __restrict__ C,
                                               ushort_t* __restrict__ Ch,
                                               ushort_t* __restrict__ Cl,
                                               int M, int N, int K) {
  int tid = threadIdx.x, lane = tid & 63, w = tid >> 6;
  int t0 = blockIdx.x * 64 + w * 16;
  int n0 = blockIdx.y * (NT * 16);
  int row = lane & 15, kg = lane >> 4;
  int KS = K >> 5;

  f32x4 acc[NT];
#pragma unroll
  for (int nt = 0; nt < NT; ++nt) acc[nt] = (f32x4){0.f, 0.f, 0.f, 0.f};

  const ushort_t* pA0 = Ah + (size_t)(t0 + row) * K + kg * 8;
  const ushort_t* pA1 = Al + (size_t)(t0 + row) * K + kg * 8;

  for (int kc = 0; kc < KS; kc += 8) {   // K-chunk of 256
    bf16x8 ah[8], al[8];
#pragma unroll
    for (int ks = 0; ks < 8; ++ks) {
      ah[ks] = *(const bf16x8*)(pA0 + (kc + ks) * 32);
      al[ks] = *(const bf16x8*)(pA1 + (kc + ks) * 32);
    }
#pragma unroll
    for (int nt = 0; nt < NT; ++nt) {
      int dt = (n0 >> 4) + nt;
      const ushort_t* pBh = Bh + ((size_t)dt * KS + kc) * 512 + lane * 8;
      const ushort_t* pBl = Bl + ((size_t)dt * KS + kc) * 512 + lane * 8;
#pragma unroll
      for (int ks = 0; ks < 8; ++ks) {
        bf16x8 bh = *(const bf16x8*)(pBh + ks * 512);
        bf16x8 bl = *(const bf16x8*)(pBl + ks * 512);
        acc[nt] = __builtin_amdgcn_mfma_f32_16x16x32_bf16(ah[ks], bh, acc[nt], 0, 0, 0);
        acc[nt] = __builtin_amdgcn_mfma_f32_16x16x32_bf16(al[ks], bh, acc[nt], 0, 0, 0);
        acc[nt] = __builtin_amdgcn_mfma_f32_16x16x32_bf16(ah[ks], bl, acc[nt], 0, 0, 0);
        acc[nt] = __builtin_amdgcn_mfma_f32_16x16x32_bf16(al[ks], bl, acc[nt], 0, 0, 0);
      }
    }
  }

#pragma unroll
  for (int nt = 0; nt < NT; ++nt) {
    int cc = n0 + nt * 16 + row;
#pragma unroll
    for (int r = 0; r < 4; ++r) {
      float v = acc[nt][r];
      if (RELU) v = fmaxf(v, 0.f);
      size_t o = (size_t)(t0 + kg * 4 + r) * N + cc;
      if (OSPLIT) {
        ushort_t h = f2bf(v);
        Ch[o] = h;
        Cl[o] = f2bf(v - bf2f(h));
      } else {
        C[o] = v;
      }
    }
  }
}

// ---------------- k_mix: G[nn][t][k] = sum_m Ahat[n0+nn][m]*relu(P[m][k]+q[m]V[t][k]) ----------------
__global__ __launch_bounds__(256) void k_mix(const float* __restrict__ V,
                                             const float* __restrict__ P,
                                             const float* __restrict__ Ahat,
                                             const float* __restrict__ q,
                                             ushort_t* __restrict__ Gh,
                                             ushort_t* __restrict__ Gl,
                                             int n0, int nch) {
  int t = blockIdx.x;
  int k = threadIdx.x;
  float v = V[(size_t)t * DG + k];
  float r[NN];
#pragma unroll
  for (int m = 0; m < NN; ++m)
    r[m] = fmaxf(fmaf(q[m], v, P[m * DG + k]), 0.f);
  for (int nn = 0; nn < nch; ++nn) {
    const float* arow = &Ahat[(size_t)(n0 + nn) * NN];  // uniform -> s_loads
    float acc = 0.f;
#pragma unroll
    for (int m = 0; m < NN; ++m)
      acc = fmaf(arow[m], r[m], acc);
    size_t idx = ((size_t)nn * T_TOK + t) * DG + k;
    ushort_t h = f2bf(acc);
    Gh[idx] = h;
    Gl[idx] = f2bf(acc - bf2f(h));
  }
}

// ---------------- k_zgemm (MFMA split-bf16) — verified round 8 ----------------
__global__ __launch_bounds__(256, 2) void k_zgemm(const ushort_t* __restrict__ Gh,
                                                  const ushort_t* __restrict__ Gl,
                                                  const ushort_t* __restrict__ Wh,
                                                  const ushort_t* __restrict__ Wl,
                                                  const float* __restrict__ w3p,
                                                  float* __restrict__ s2T,
                                                  int n0) {
  int tid = threadIdx.x, lane = tid & 63, w = tid >> 6;
  int ny = blockIdx.y;
  int t0 = blockIdx.x * 64 + w * 16;
  int row = lane & 15, kg = lane >> 4;

  const ushort_t* Ah = Gh + ((size_t)ny * T_TOK + t0 + row) * DG + kg * 8;
  const ushort_t* Al = Gl + ((size_t)ny * T_TOK + t0 + row) * DG + kg * 8;
  bf16x8 ah[8], al[8];
#pragma unroll
  for (int ks = 0; ks < 8; ++ks) {
    ah[ks] = *(const bf16x8*)(Ah + ks * 32);
    al[ks] = *(const bf16x8*)(Al + ks * 32);
  }

  float wp[16];
#pragma unroll
  for (int dt = 0; dt < 16; ++dt) wp[dt] = w3p[dt * 16 + row];

  f32x4 acc[16];
#pragma unroll
  for (int dt = 0; dt < 16; ++dt) acc[dt] = (f32x4){0.f, 0.f, 0.f, 0.f};

#pragma unroll
  for (int dt = 0; dt < 16; ++dt) {
    const ushort_t* Bh = Wh + (size_t)dt * 4096 + lane * 8;
    const ushort_t* Bl = Wl + (size_t)dt * 4096 + lane * 8;
#pragma unroll
    for (int ks = 0; ks < 8; ++ks) {
      bf16x8 bh = *(const bf16x8*)(Bh + ks * 512);
      bf16x8 bl = *(const bf16x8*)(Bl + ks * 512);
      acc[dt] = __builtin_amdgcn_mfma_f32_16x16x32_bf16(ah[ks], bh, acc[dt], 0, 0, 0);
      acc[dt] = __builtin_amdgcn_mfma_f32_16x16x32_bf16(al[ks], bh, acc[dt], 0, 0, 0);
      acc[dt] = __builtin_amdgcn_mfma_f32_16x16x32_bf16(ah[ks], bl, acc[dt], 0, 0, 0);
      acc[dt] = __builtin_amdgcn_mfma_f32_16x16x32_bf16(al[ks], bl, acc[dt], 0, 0, 0);
    }
  }

  float v0 = 0.f, v1 = 0.f, v2 = 0.f, v3 = 0.f;
#pragma unroll
  for (int dt = 0; dt < 16; ++dt) {
    float wpd = wp[dt];
    v0 = fmaf(fmaxf(acc[dt][0], 0.f), wpd, v0);
    v1 = fmaf(fmaxf(acc[dt][1], 0.f), wpd, v1);
    v2 = fmaf(fmaxf(acc[dt][2], 0.f), wpd, v2);
    v3 = fmaf(fmaxf(acc[dt][3], 0.f), wpd, v3);
  }
#pragma unroll
  for (int off = 1; off < 16; off <<= 1) {
    v0 += __shfl_xor(v0, off, 64);
    v1 += __shfl_xor(v1, off, 64);
    v2 += __shfl_xor(v2, off, 64);
    v3 += __shfl_xor(v3, off, 64);
  }
  if (row == 0) {
    int t = t0 + kg * 4;
    int n = n0 + ny;
    s2T[(size_t)(t + 0) * NN + n] = v0;
    s2T[(size_t)(t + 1) * NN + n] = v1;
    s2T[(size_t)(t + 2) * NN + n] = v2;
    s2T[(size_t)(t + 3) * NN + n] = v3;
  }
}

// ---------------- final: scores[t][j] = sum_m Ahat[j][m]*s2T[t][m]; softmax ----------------
__global__ __launch_bounds__(64) void k_final(const float* __restrict__ s2T,
                                              const float* __restrict__ Ahat,
                                              float* __restrict__ out) {
  __shared__ float s2l[NN];
  int t = blockIdx.x;
  int j = threadIdx.x;
  s2l[j] = s2T[(size_t)t * NN + j];
  if (j == 0) s2l[NEXP] = s2T[(size_t)t * NN + NEXP];
  __syncthreads();
  float sc = 0.f;
  for (int m = 0; m < NN; ++m)
    sc = fmaf(Ahat[j * NN + m], s2l[m], sc);
  float mx = sc;
#pragma unroll
  for (int off = 32; off > 0; off >>= 1)
    mx = fmaxf(mx, __shfl_xor(mx, off, 64));
  float e = expf(sc - mx);
  float sum = e;
#pragma unroll
  for (int off = 32; off > 0; off >>= 1)
    sum += __shfl_xor(sum, off, 64);
  out[(size_t)t * NEXP + j] = e / sum;
}

// ---------------- launch ----------------
extern "C" void kernel_launch(void* const* d_in, const int* in_sizes, int n_in,
                              void* d_out, int out_size, void* d_ws, size_t ws_size,
                              hipStream_t stream) {
  (void)in_sizes; (void)n_in; (void)out_size; (void)ws_size;
  const float* x   = (const float*)d_in[0];
  const float* Xp  = (const float*)d_in[1];
  const float* mlp = (const float*)d_in[2];
  const float* W0  = (const float*)d_in[3];
  const float* W1  = (const float*)d_in[4];
  const float* W2  = (const float*)d_in[5];
  const float* W3  = (const float*)d_in[6];
  const float* pw  = (const float*)d_in[7];
  float* out = (float*)d_out;
  float* ws = (float*)d_ws;

  // workspace layout (floats), total 18,934,752 fl ~= 75.7 MB (< 82 MB proven)
  float* expT  = ws + 0;         // 65536
  float* expTT = ws + 65536;     // 65536 (dead after k_cos -> W2f overlay)
  float* w3p   = ws + 131072;    // 256
  float* D     = ws + 131328;    // 4096
  float* Ahat  = ws + 135424;    // 4240
  float* q     = ws + 139664;    // 80
  float* expW  = ws + 139744;    // 16384
  float* CW1   = ws + 156128;    // 16640
  float* P     = ws + 172768;    // 16640
  float* s2T   = ws + 189408;    // 133120
  float* V     = ws + 322528;    // 524288
  float* part  = ws + 846816;    // 524288 (expT K-split partials; dead early)
  ushort_t* W01f_h = (ushort_t*)(ws + 1371104);  // 262144 us = 131072 fl
  ushort_t* W01f_l = (ushort_t*)(ws + 1502176);  // 131072 fl
  // big arena at 1633248: split planes (dead before k_mix) overlaid by Gc
  float* arena = ws + 1633248;
  ushort_t* Xh    = (ushort_t*)(arena);                 // 2M us = 1048576 fl
  ushort_t* Xl    = (ushort_t*)(arena + 1048576);       // 1048576 fl
  ushort_t* mlpf_h = (ushort_t*)(arena + 2097152);      // 524288 fl
  ushort_t* mlpf_l = (ushort_t*)(arena + 2621440);      // 524288 fl
  ushort_t* XTh   = (ushort_t*)(arena + 3145728);       // 1048576 fl
  ushort_t* XTl   = (ushort_t*)(arena + 4194304);       // 1048576 fl
  ushort_t* Gc_h  = (ushort_t*)(arena);                 // 8650752 fl (overlays splits)
  ushort_t* Gc_l  = (ushort_t*)(arena + 8650752);       // 8650752 fl
  ushort_t* W2f_h = (ushort_t*)(ws + 65536);            // 32768 fl (overlay expTT)
  ushort_t* W2f_l = (ushort_t*)(ws + 65536 + 32768);    // 32768 fl

  // expert MLP (K-split, fp32 for the cos-threshold path)
  k_expT_ks<<<dim3(4, 16, 8), dim3(256), 0, stream>>>(Xp, mlp, part);
  k_expT_red<<<dim3(256), dim3(256), 0, stream>>>(part, expT, expTT);
  // independent setup
  k_W01<<<dim3(1024), dim3(256), 0, stream>>>(W0, W1, W01f_h, W01f_l);
  k_w3p<<<dim3(256), dim3(256), 0, stream>>>(W3, pw, w3p);
  k_splitX<<<dim3(1024), dim3(256), 0, stream>>>(x, Xh, Xl);
  k_splitB<<<dim3(128, 4), dim3(256), 0, stream>>>(mlp, mlpf_h, mlpf_l, DIM, DIM);
  // graph build
  k_cos<<<dim3(64), dim3(256), 0, stream>>>(expTT, D);
  k_splitW2<<<dim3(256), dim3(256), 0, stream>>>(W2, W2f_h, W2f_l);  // after k_cos
  k_buildA<<<dim3(1), dim3(256), 0, stream>>>(D, Ahat, q);
  k_expW<<<dim3(64), dim3(256), 0, stream>>>(expT, W0, expW);
  k_CW1<<<dim3(65), dim3(256), 0, stream>>>(Ahat, expW, W1, CW1);
  k_P<<<dim3(65), dim3(256), 0, stream>>>(Ahat, CW1, P);
  // XT = relu(x@mlp) as bf16 hi/lo (MFMA), then V = XT@W01 fp32 (MFMA)
  k_mgemm<8, true, true><<<dim3(32, 8), dim3(256), 0, stream>>>(
      Xh, Xl, mlpf_h, mlpf_l, nullptr, XTh, XTl, T_TOK, DIM, DIM);
  k_mgemm<4, false, false><<<dim3(32, 4), dim3(256), 0, stream>>>(
      XTh, XTl, W01f_h, W01f_l, V, nullptr, nullptr, T_TOK, DG, DIM);
  // chunked: G (bf16 hi/lo) = Ahat-mix; s2 = reduce(relu(G@W2)*w3p) via MFMA
  k_mix<<<dim3(T_TOK), dim3(256), 0, stream>>>(V, P, Ahat, q, Gc_h, Gc_l, 0, 33);
  k_zgemm<<<dim3(32, 33), dim3(256), 0, stream>>>(Gc_h, Gc_l, W2f_h, W2f_l, w3p, s2T, 0);
  k_mix<<<dim3(T_TOK), dim3(256), 0, stream>>>(V, P, Ahat, q, Gc_h, Gc_l, 33, 32);
  k_zgemm<<<dim3(32, 32), dim3(256), 0, stream>>>(Gc_h, Gc_l, W2f_h, W2f_l, w3p, s2T, 33);
  // scores + softmax -> out [2048,64]
  k_final<<<dim3(T_TOK), dim3(64), 0, stream>>>(s2T, Ahat, out);
}

// Round 10
// 555.791 us; speedup vs baseline: 2.1545x; 1.1010x over previous
//
#include <hip/hip_runtime.h>
#include <hip/hip_bf16.h>
#include <math.h>

#define DIM 1024
#define NEXP 64
#define NN 65
#define DG 256
#define T_TOK 2048
#define THR_EDGE 0.5f

typedef __attribute__((ext_vector_type(8))) short bf16x8;
typedef __attribute__((ext_vector_type(4))) float f32x4;
typedef unsigned short ushort_t;
typedef __attribute__((ext_vector_type(8))) unsigned short us8;

// RNE float->bf16 (raw ushort) and back
static __device__ __forceinline__ ushort_t f2bf(float x) {
  unsigned u = __float_as_uint(x);
  unsigned r = (u + 0x7FFFu + ((u >> 16) & 1u)) >> 16;
  return (ushort_t)r;
}
static __device__ __forceinline__ float bf2f(ushort_t h) {
  return __uint_as_float(((unsigned)h) << 16);
}

// ---------------- setup kernels ----------------

// K-split expT partials: part[kc][i][j] = sum_{k in chunk} Xp[k][i]*mlp[k][j]
__global__ __launch_bounds__(256) void k_expT_ks(const float* __restrict__ Xp,
                                                 const float* __restrict__ mlp,
                                                 float* __restrict__ part) {
  int i0 = blockIdx.y * 4;
  int j = blockIdx.x * 256 + threadIdx.x;
  int k0 = blockIdx.z * 128;
  float acc0 = 0.f, acc1 = 0.f, acc2 = 0.f, acc3 = 0.f;
#pragma unroll 4
  for (int k = k0; k < k0 + 128; ++k) {
    float m = mlp[(size_t)k * DIM + j];            // coalesced
    const float* xr = &Xp[(size_t)k * NEXP + i0];  // uniform -> s_load
    acc0 = fmaf(xr[0], m, acc0);
    acc1 = fmaf(xr[1], m, acc1);
    acc2 = fmaf(xr[2], m, acc2);
    acc3 = fmaf(xr[3], m, acc3);
  }
  size_t base = ((size_t)blockIdx.z * NEXP + i0) * DIM + j;
  part[base + 0 * DIM] = acc0;
  part[base + 1 * DIM] = acc1;
  part[base + 2 * DIM] = acc2;
  part[base + 3 * DIM] = acc3;
}

// reduce partials: expT[i][j] = relu(sum_kc part), also expTT[j][i]
__global__ __launch_bounds__(256) void k_expT_red(const float* __restrict__ part,
                                                  float* __restrict__ expT,
                                                  float* __restrict__ expTT) {
  int e = blockIdx.x * 256 + threadIdx.x;   // 64K elems
  int i = e >> 10, j = e & 1023;
  float v = 0.f;
#pragma unroll
  for (int kc = 0; kc < 8; ++kc)
    v += part[(size_t)kc * (NEXP * DIM) + e];
  v = fmaxf(v, 0.f);
  expT[e] = v;
  expTT[(size_t)j * NEXP + i] = v;
}

// W01 = W0@W1, emitted directly as frag-major bf16 hi/lo (B-operand, K=1024,N=256)
__global__ __launch_bounds__(256) void k_W01(const float* __restrict__ W0,
                                             const float* __restrict__ W1,
                                             ushort_t* __restrict__ Bh,
                                             ushort_t* __restrict__ Bl) {
  int i = blockIdx.x;      // k-dim (1024)
  int d = threadIdx.x;     // n-dim (256)
  float acc = 0.f;
#pragma unroll 4
  for (int k = 0; k < DG; ++k)
    acc = fmaf(W0[i * DG + k], W1[k * DG + d], acc);
  int dt = d >> 4, c = d & 15, ks = i >> 5, kg = (i >> 3) & 3, j = i & 7;
  size_t idx = (((size_t)dt * 32 + ks) * 64 + kg * 16 + c) * 8 + j;
  ushort_t h = f2bf(acc);
  Bh[idx] = h;
  Bl[idx] = f2bf(acc - bf2f(h));
}

// w3p[i] = dot(W3 row i, pw) — one block per i
__global__ __launch_bounds__(256) void k_w3p(const float* __restrict__ W3,
                                             const float* __restrict__ pw,
                                             float* __restrict__ w3p) {
  __shared__ float red[4];
  int i = blockIdx.x;
  int tid = threadIdx.x, lane = tid & 63, w = tid >> 6;
  const float* r = &W3[(size_t)i * DIM];
  float s = r[tid] * pw[tid]
          + r[tid + 256] * pw[tid + 256]
          + r[tid + 512] * pw[tid + 512]
          + r[tid + 768] * pw[tid + 768];
#pragma unroll
  for (int off = 32; off > 0; off >>= 1)
    s += __shfl_down(s, off, 64);
  if (lane == 0) red[w] = s;
  __syncthreads();
  if (tid == 0) w3p[i] = red[0] + red[1] + red[2] + red[3];
}

// split x into bf16 hi/lo row-major planes (A-operand)
__global__ __launch_bounds__(256) void k_splitX(const float* __restrict__ X,
                                                ushort_t* __restrict__ Xh,
                                                ushort_t* __restrict__ Xl) {
  size_t base = ((size_t)blockIdx.x * 256 + threadIdx.x) * 8;
  us8 h, l;
#pragma unroll
  for (int u = 0; u < 8; ++u) {
    float v = X[base + u];
    ushort_t hh = f2bf(v);
    h[u] = hh;
    l[u] = f2bf(v - bf2f(hh));
  }
  *(us8*)(Xh + base) = h;
  *(us8*)(Xl + base) = l;
}

// split B [K][N] fp32 into frag-major bf16 hi/lo. thread = (k0 8-aligned, n)
__global__ __launch_bounds__(256) void k_splitB(const float* __restrict__ B,
                                                ushort_t* __restrict__ Bh,
                                                ushort_t* __restrict__ Bl,
                                                int K, int N) {
  int k0 = blockIdx.x * 8;
  int d = blockIdx.y * 256 + threadIdx.x;
  int KS = K >> 5;
  int dt = d >> 4, c = d & 15, ks = k0 >> 5, kg = (k0 >> 3) & 3;
  size_t idx = (((size_t)dt * KS + ks) * 64 + kg * 16 + c) * 8;
  us8 h, l;
#pragma unroll
  for (int j = 0; j < 8; ++j) {
    float v = B[(size_t)(k0 + j) * N + d];
    ushort_t hh = f2bf(v);
    h[j] = hh;
    l[j] = f2bf(v - bf2f(hh));
  }
  *(us8*)(Bh + idx) = h;
  *(us8*)(Bl + idx) = l;
}

// D[i][j] = dot(exp_i, exp_j); 4-way k-split per block + LDS reduce
__global__ __launch_bounds__(256) void k_cos(const float* __restrict__ expTT,
                                             float* __restrict__ D) {
  __shared__ float part[4][NEXP];
  int i = blockIdx.x;
  int tid = threadIdx.x;
  int j = tid & 63, qd = tid >> 6;
  float acc = 0.f;
  int d0 = qd * 256;
  for (int d = d0; d < d0 + 256; ++d) {
    float ei = expTT[(size_t)d * NEXP + i];
    float ej = expTT[(size_t)d * NEXP + j];
    acc = fmaf(ei, ej, acc);
  }
  part[qd][j] = acc;
  __syncthreads();
  if (tid < NEXP)
    D[i * NEXP + tid] = part[0][tid] + part[1][tid] + part[2][tid] + part[3][tid];
}

// Split W2 into bf16 hi/lo planes in MFMA-frag-major layout (K=256 -> KS=8)
__global__ __launch_bounds__(256) void k_splitW2(const float* __restrict__ W2,
                                                 ushort_t* __restrict__ Wh,
                                                 ushort_t* __restrict__ Wl) {
  int k = blockIdx.x;
  int d = threadIdx.x;
  float w = W2[(size_t)k * DG + d];
  ushort_t h = f2bf(w);
  ushort_t l = f2bf(w - bf2f(h));
  int dt = d >> 4, c = d & 15, ks = k >> 5, kg = (k >> 3) & 3, j = k & 7;
  int idx = (((dt * 8 + ks) * 64) + kg * 16 + c) * 8 + j;
  Wh[idx] = h;
  Wl[idx] = l;
}

// Build normalized adjacency Ahat [65][65] and q = Ahat @ a0
__global__ __launch_bounds__(256) void k_buildA(const float* __restrict__ D,
                                                float* __restrict__ Ahat,
                                                float* __restrict__ q) {
  __shared__ float nrm[NEXP];
  __shared__ float Ar[NN][NN];
  __shared__ float Al[NN][NN];
  __shared__ float dd[NN];
  __shared__ float a0[NN];
  int tid = threadIdx.x;
  if (tid < NEXP) nrm[tid] = fmaxf(sqrtf(D[tid * NEXP + tid]), 1e-8f);
  __syncthreads();
  for (int e = tid; e < NN * NN; e += 256) {
    int n = e / NN, m = e - n * NN;
    float v = 0.f;
    if (n == m) v = 1.f;                              // self loop
    else if (m == NEXP) v = (n < NEXP) ? 1.f : 0.f;   // token -> each expert
    else if (n < NEXP && m < n) {                     // edge m->n for m<n
      float c = D[m * NEXP + n] / (nrm[m] * nrm[n]);
      v = (c > THR_EDGE) ? 1.f : 0.f;
    }
    Ar[n][m] = v;
  }
  __syncthreads();
  if (tid < NN) {
    float s = 0.f;
    for (int m = 0; m < NN; ++m) s += Ar[tid][m];
    dd[tid] = 1.0f / sqrtf(s);
  }
  __syncthreads();
  for (int e = tid; e < NN * NN; e += 256) {
    int n = e / NN, m = e - n * NN;
    float v = Ar[n][m] * dd[n] * dd[m];
    Al[n][m] = v;
    Ahat[e] = v;
  }
  __syncthreads();
  if (tid < NN) a0[tid] = Al[tid][NEXP];
  __syncthreads();
  if (tid < NN) {
    float s = 0.f;
    for (int m = 0; m < NN; ++m) s = fmaf(Al[tid][m], a0[m], s);
    q[tid] = s;
  }
}

// expW[m][d] = sum_k expT[m][k] * W0[k][d]
__global__ __launch_bounds__(256) void k_expW(const float* __restrict__ expT,
                                              const float* __restrict__ W0,
                                              float* __restrict__ expW) {
  int m = blockIdx.x, d = threadIdx.x;
  float acc = 0.f;
#pragma unroll 4
  for (int k = 0; k < DIM; ++k)
    acc = fmaf(expT[m * DIM + k], W0[k * DG + d], acc);
  expW[m * DG + d] = acc;
}

// CW1[n][d] = ((Ahat[:, :64] @ expW) @ W1)[n][d]
__global__ __launch_bounds__(256) void k_CW1(const float* __restrict__ Ahat,
                                             const float* __restrict__ expW,
                                             const float* __restrict__ W1,
                                             float* __restrict__ CW1) {
  __shared__ float c0[DG];
  int n = blockIdx.x, d = threadIdx.x;
  float acc = 0.f;
  for (int m = 0; m < NEXP; ++m)
    acc = fmaf(Ahat[n * NN + m], expW[m * DG + d], acc);
  c0[d] = acc;
  __syncthreads();
  float b = 0.f;
#pragma unroll 4
  for (int k = 0; k < DG; ++k)
    b = fmaf(c0[k], W1[k * DG + d], b);
  CW1[n * DG + d] = b;
}

// P[n][d] = (Ahat @ CW1)[n][d]
__global__ __launch_bounds__(256) void k_P(const float* __restrict__ Ahat,
                                           const float* __restrict__ CW1,
                                           float* __restrict__ P) {
  int n = blockIdx.x, d = threadIdx.x;
  float acc = 0.f;
  for (int m = 0; m < NN; ++m)
    acc = fmaf(Ahat[n * NN + m], CW1[m * DG + d], acc);
  P[n * DG + d] = acc;
}

// ---------------- k_mgemm v2: MFMA split-bf16 GEMM C = [relu](A@B) ----------------
// Fix for round-9's latency wall (MfmaUtil 7.4%, 1 block/CU): smaller NT for more
// blocks, and B-frag loads batched 16-at-a-time per nt so ~16 loads are in flight
// (compiler hoists nt+1 loads under nt's MFMA chain). Fragment math unchanged.
template <int NT, bool RELU, bool OSPLIT>
__global__ __launch_bounds__(256) void k_mgemm(const ushort_t* __restrict__ Ah,
                                               const ushort_t* __restrict__ Al,
                                               const ushort_t* __restrict__ Bh,
                                               const ushort_t* __restrict__ Bl,
                                               float* __restrict__ C,
                                               ushort_t* __restrict__ Ch,
                                               ushort_t* __restrict__ Cl,
                                               int M, int N, int K) {
  int tid = threadIdx.x, lane = tid & 63, w = tid >> 6;
  int t0 = blockIdx.x * 64 + w * 16;
  int n0 = blockIdx.y * (NT * 16);
  int row = lane & 15, kg = lane >> 4;
  int KS = K >> 5;

  f32x4 acc[NT];
#pragma unroll
  for (int nt = 0; nt < NT; ++nt) acc[nt] = (f32x4){0.f, 0.f, 0.f, 0.f};

  const ushort_t* pA0 = Ah + (size_t)(t0 + row) * K + kg * 8;
  const ushort_t* pA1 = Al + (size_t)(t0 + row) * K + kg * 8;

  for (int kc = 0; kc < KS; kc += 8) {   // K-chunk of 256
    bf16x8 ah[8], al[8];
#pragma unroll
    for (int ks = 0; ks < 8; ++ks) {
      ah[ks] = *(const bf16x8*)(pA0 + (kc + ks) * 32);
      al[ks] = *(const bf16x8*)(pA1 + (kc + ks) * 32);
    }
#pragma unroll
    for (int nt = 0; nt < NT; ++nt) {
      int dt = (n0 >> 4) + nt;
      const ushort_t* pBh = Bh + ((size_t)dt * KS + kc) * 512 + lane * 8;
      const ushort_t* pBl = Bl + ((size_t)dt * KS + kc) * 512 + lane * 8;
      // batch all 16 B-frag loads (independent) before the MFMA chain
      bf16x8 bh[8], bl[8];
#pragma unroll
      for (int ks = 0; ks < 8; ++ks) {
        bh[ks] = *(const bf16x8*)(pBh + ks * 512);
        bl[ks] = *(const bf16x8*)(pBl + ks * 512);
      }
#pragma unroll
      for (int ks = 0; ks < 8; ++ks) {
        acc[nt] = __builtin_amdgcn_mfma_f32_16x16x32_bf16(ah[ks], bh[ks], acc[nt], 0, 0, 0);
        acc[nt] = __builtin_amdgcn_mfma_f32_16x16x32_bf16(al[ks], bh[ks], acc[nt], 0, 0, 0);
        acc[nt] = __builtin_amdgcn_mfma_f32_16x16x32_bf16(ah[ks], bl[ks], acc[nt], 0, 0, 0);
        acc[nt] = __builtin_amdgcn_mfma_f32_16x16x32_bf16(al[ks], bl[ks], acc[nt], 0, 0, 0);
      }
    }
  }

#pragma unroll
  for (int nt = 0; nt < NT; ++nt) {
    int cc = n0 + nt * 16 + row;
#pragma unroll
    for (int r = 0; r < 4; ++r) {
      float v = acc[nt][r];
      if (RELU) v = fmaxf(v, 0.f);
      size_t o = (size_t)(t0 + kg * 4 + r) * N + cc;
      if (OSPLIT) {
        ushort_t h = f2bf(v);
        Ch[o] = h;
        Cl[o] = f2bf(v - bf2f(h));
      } else {
        C[o] = v;
      }
    }
  }
}

// ---------------- k_mix: G[nn][t][k] = sum_m Ahat[n0+nn][m]*relu(P[m][k]+q[m]V[t][k]) ----------------
__global__ __launch_bounds__(256) void k_mix(const float* __restrict__ V,
                                             const float* __restrict__ P,
                                             const float* __restrict__ Ahat,
                                             const float* __restrict__ q,
                                             ushort_t* __restrict__ Gh,
                                             ushort_t* __restrict__ Gl,
                                             int n0, int nch) {
  int t = blockIdx.x;
  int k = threadIdx.x;
  float v = V[(size_t)t * DG + k];
  float r[NN];
#pragma unroll
  for (int m = 0; m < NN; ++m)
    r[m] = fmaxf(fmaf(q[m], v, P[m * DG + k]), 0.f);
  for (int nn = 0; nn < nch; ++nn) {
    const float* arow = &Ahat[(size_t)(n0 + nn) * NN];  // uniform -> s_loads
    float acc = 0.f;
#pragma unroll
    for (int m = 0; m < NN; ++m)
      acc = fmaf(arow[m], r[m], acc);
    size_t idx = ((size_t)nn * T_TOK + t) * DG + k;
    ushort_t h = f2bf(acc);
    Gh[idx] = h;
    Gl[idx] = f2bf(acc - bf2f(h));
  }
}

// ---------------- k_zgemm (MFMA split-bf16) — verified round 8 ----------------
__global__ __launch_bounds__(256, 2) void k_zgemm(const ushort_t* __restrict__ Gh,
                                                  const ushort_t* __restrict__ Gl,
                                                  const ushort_t* __restrict__ Wh,
                                                  const ushort_t* __restrict__ Wl,
                                                  const float* __restrict__ w3p,
                                                  float* __restrict__ s2T,
                                                  int n0) {
  int tid = threadIdx.x, lane = tid & 63, w = tid >> 6;
  int ny = blockIdx.y;
  int t0 = blockIdx.x * 64 + w * 16;
  int row = lane & 15, kg = lane >> 4;

  const ushort_t* Ah = Gh + ((size_t)ny * T_TOK + t0 + row) * DG + kg * 8;
  const ushort_t* Al = Gl + ((size_t)ny * T_TOK + t0 + row) * DG + kg * 8;
  bf16x8 ah[8], al[8];
#pragma unroll
  for (int ks = 0; ks < 8; ++ks) {
    ah[ks] = *(const bf16x8*)(Ah + ks * 32);
    al[ks] = *(const bf16x8*)(Al + ks * 32);
  }

  float wp[16];
#pragma unroll
  for (int dt = 0; dt < 16; ++dt) wp[dt] = w3p[dt * 16 + row];

  f32x4 acc[16];
#pragma unroll
  for (int dt = 0; dt < 16; ++dt) acc[dt] = (f32x4){0.f, 0.f, 0.f, 0.f};

#pragma unroll
  for (int dt = 0; dt < 16; ++dt) {
    const ushort_t* Bh = Wh + (size_t)dt * 4096 + lane * 8;
    const ushort_t* Bl = Wl + (size_t)dt * 4096 + lane * 8;
#pragma unroll
    for (int ks = 0; ks < 8; ++ks) {
      bf16x8 bh = *(const bf16x8*)(Bh + ks * 512);
      bf16x8 bl = *(const bf16x8*)(Bl + ks * 512);
      acc[dt] = __builtin_amdgcn_mfma_f32_16x16x32_bf16(ah[ks], bh, acc[dt], 0, 0, 0);
      acc[dt] = __builtin_amdgcn_mfma_f32_16x16x32_bf16(al[ks], bh, acc[dt], 0, 0, 0);
      acc[dt] = __builtin_amdgcn_mfma_f32_16x16x32_bf16(ah[ks], bl, acc[dt], 0, 0, 0);
      acc[dt] = __builtin_amdgcn_mfma_f32_16x16x32_bf16(al[ks], bl, acc[dt], 0, 0, 0);
    }
  }

  float v0 = 0.f, v1 = 0.f, v2 = 0.f, v3 = 0.f;
#pragma unroll
  for (int dt = 0; dt < 16; ++dt) {
    float wpd = wp[dt];
    v0 = fmaf(fmaxf(acc[dt][0], 0.f), wpd, v0);
    v1 = fmaf(fmaxf(acc[dt][1], 0.f), wpd, v1);
    v2 = fmaf(fmaxf(acc[dt][2], 0.f), wpd, v2);
    v3 = fmaf(fmaxf(acc[dt][3], 0.f), wpd, v3);
  }
#pragma unroll
  for (int off = 1; off < 16; off <<= 1) {
    v0 += __shfl_xor(v0, off, 64);
    v1 += __shfl_xor(v1, off, 64);
    v2 += __shfl_xor(v2, off, 64);
    v3 += __shfl_xor(v3, off, 64);
  }
  if (row == 0) {
    int t = t0 + kg * 4;
    int n = n0 + ny;
    s2T[(size_t)(t + 0) * NN + n] = v0;
    s2T[(size_t)(t + 1) * NN + n] = v1;
    s2T[(size_t)(t + 2) * NN + n] = v2;
    s2T[(size_t)(t + 3) * NN + n] = v3;
  }
}

// ---------------- final: scores[t][j] = sum_m Ahat[j][m]*s2T[t][m]; softmax ----------------
__global__ __launch_bounds__(64) void k_final(const float* __restrict__ s2T,
                                              const float* __restrict__ Ahat,
                                              float* __restrict__ out) {
  __shared__ float s2l[NN];
  int t = blockIdx.x;
  int j = threadIdx.x;
  s2l[j] = s2T[(size_t)t * NN + j];
  if (j == 0) s2l[NEXP] = s2T[(size_t)t * NN + NEXP];
  __syncthreads();
  float sc = 0.f;
  for (int m = 0; m < NN; ++m)
    sc = fmaf(Ahat[j * NN + m], s2l[m], sc);
  float mx = sc;
#pragma unroll
  for (int off = 32; off > 0; off >>= 1)
    mx = fmaxf(mx, __shfl_xor(mx, off, 64));
  float e = expf(sc - mx);
  float sum = e;
#pragma unroll
  for (int off = 32; off > 0; off >>= 1)
    sum += __shfl_xor(sum, off, 64);
  out[(size_t)t * NEXP + j] = e / sum;
}

// ---------------- launch ----------------
extern "C" void kernel_launch(void* const* d_in, const int* in_sizes, int n_in,
                              void* d_out, int out_size, void* d_ws, size_t ws_size,
                              hipStream_t stream) {
  (void)in_sizes; (void)n_in; (void)out_size; (void)ws_size;
  const float* x   = (const float*)d_in[0];
  const float* Xp  = (const float*)d_in[1];
  const float* mlp = (const float*)d_in[2];
  const float* W0  = (const float*)d_in[3];
  const float* W1  = (const float*)d_in[4];
  const float* W2  = (const float*)d_in[5];
  const float* W3  = (const float*)d_in[6];
  const float* pw  = (const float*)d_in[7];
  float* out = (float*)d_out;
  float* ws = (float*)d_ws;

  // workspace layout (floats), total 18,934,752 fl ~= 75.7 MB — same as round 9
  float* expT  = ws + 0;         // 65536
  float* expTT = ws + 65536;     // 65536 (dead after k_cos -> W2f overlay)
  float* w3p   = ws + 131072;    // 256
  float* D     = ws + 131328;    // 4096
  float* Ahat  = ws + 135424;    // 4240
  float* q     = ws + 139664;    // 80
  float* expW  = ws + 139744;    // 16384
  float* CW1   = ws + 156128;    // 16640
  float* P     = ws + 172768;    // 16640
  float* s2T   = ws + 189408;    // 133120
  float* V     = ws + 322528;    // 524288
  float* part  = ws + 846816;    // 524288 (expT K-split partials; dead early)
  ushort_t* W01f_h = (ushort_t*)(ws + 1371104);  // 131072 fl
  ushort_t* W01f_l = (ushort_t*)(ws + 1502176);  // 131072 fl
  // big arena at 1633248: split planes (dead before k_mix) overlaid by Gc
  float* arena = ws + 1633248;
  ushort_t* Xh    = (ushort_t*)(arena);                 // 1048576 fl
  ushort_t* Xl    = (ushort_t*)(arena + 1048576);       // 1048576 fl
  ushort_t* mlpf_h = (ushort_t*)(arena + 2097152);      // 524288 fl
  ushort_t* mlpf_l = (ushort_t*)(arena + 2621440);      // 524288 fl
  ushort_t* XTh   = (ushort_t*)(arena + 3145728);       // 1048576 fl
  ushort_t* XTl   = (ushort_t*)(arena + 4194304);       // 1048576 fl
  ushort_t* Gc_h  = (ushort_t*)(arena);                 // 8650752 fl (overlays splits)
  ushort_t* Gc_l  = (ushort_t*)(arena + 8650752);       // 8650752 fl
  ushort_t* W2f_h = (ushort_t*)(ws + 65536);            // 32768 fl (overlay expTT)
  ushort_t* W2f_l = (ushort_t*)(ws + 65536 + 32768);    // 32768 fl

  // expert MLP (K-split, fp32 for the cos-threshold path)
  k_expT_ks<<<dim3(4, 16, 8), dim3(256), 0, stream>>>(Xp, mlp, part);
  k_expT_red<<<dim3(256), dim3(256), 0, stream>>>(part, expT, expTT);
  // independent setup
  k_W01<<<dim3(1024), dim3(256), 0, stream>>>(W0, W1, W01f_h, W01f_l);
  k_w3p<<<dim3(256), dim3(256), 0, stream>>>(W3, pw, w3p);
  k_splitX<<<dim3(1024), dim3(256), 0, stream>>>(x, Xh, Xl);
  k_splitB<<<dim3(128, 4), dim3(256), 0, stream>>>(mlp, mlpf_h, mlpf_l, DIM, DIM);
  // graph build
  k_cos<<<dim3(64), dim3(256), 0, stream>>>(expTT, D);
  k_splitW2<<<dim3(256), dim3(256), 0, stream>>>(W2, W2f_h, W2f_l);  // after k_cos
  k_buildA<<<dim3(1), dim3(256), 0, stream>>>(D, Ahat, q);
  k_expW<<<dim3(64), dim3(256), 0, stream>>>(expT, W0, expW);
  k_CW1<<<dim3(65), dim3(256), 0, stream>>>(Ahat, expW, W1, CW1);
  k_P<<<dim3(65), dim3(256), 0, stream>>>(Ahat, CW1, P);
  // XT = relu(x@mlp) as bf16 hi/lo (MFMA, NT=4 -> 512 blocks = 2/CU)
  k_mgemm<4, true, true><<<dim3(32, 16), dim3(256), 0, stream>>>(
      Xh, Xl, mlpf_h, mlpf_l, nullptr, XTh, XTl, T_TOK, DIM, DIM);
  // V = XT@W01 fp32 (MFMA, NT=2 -> 256 blocks)
  k_mgemm<2, false, false><<<dim3(32, 8), dim3(256), 0, stream>>>(
      XTh, XTl, W01f_h, W01f_l, V, nullptr, nullptr, T_TOK, DG, DIM);
  // chunked: G (bf16 hi/lo) = Ahat-mix; s2 = reduce(relu(G@W2)*w3p) via MFMA
  k_mix<<<dim3(T_TOK), dim3(256), 0, stream>>>(V, P, Ahat, q, Gc_h, Gc_l, 0, 33);
  k_zgemm<<<dim3(32, 33), dim3(256), 0, stream>>>(Gc_h, Gc_l, W2f_h, W2f_l, w3p, s2T, 0);
  k_mix<<<dim3(T_TOK), dim3(256), 0, stream>>>(V, P, Ahat, q, Gc_h, Gc_l, 33, 32);
  k_zgemm<<<dim3(32, 32), dim3(256), 0, stream>>>(Gc_h, Gc_l, W2f_h, W2f_l, w3p, s2T, 33);
  // scores + softmax -> out [2048,64]
  k_final<<<dim3(T_TOK), dim3(64), 0, stream>>>(s2T, Ahat, out);
}